// Round 5
// baseline (400.902 us; speedup 1.0000x reference)
//
#include <hip/hip_runtime.h>
#include <math.h>

#define N_NODES 100000
#define F_IN    128
#define HID     64
#define N_CLS   40
#define MT      (N_NODES / 16)                  // 6250 M-tiles of 16 nodes
#define NS1     ((N_NODES + 1023) / 1024)       // 98 scan blocks

typedef __attribute__((ext_vector_type(8))) short bf8_t;   // 8 bf16 (4 VGPR)
typedef __attribute__((ext_vector_type(4))) float f4_t;    // MFMA C/D frag
typedef __attribute__((ext_vector_type(2))) float f2v_t;

typedef unsigned short ushort_t;
typedef unsigned int uint_t;
typedef unsigned char uchar_t;

__device__ __forceinline__ ushort_t f2b(float f) {   // f32 -> bf16 RNE
    union { float f; uint_t u; } c; c.f = f;
    uint_t u = c.u + 0x7FFFu + ((c.u >> 16) & 1u);
    return (ushort_t)(u >> 16);
}
__device__ __forceinline__ float b2f(ushort_t h) {
    union { uint_t u; float f; } c; c.u = ((uint_t)h) << 16;
    return c.f;
}

// ---- fp8 e4m3 (OCP) helpers: HW cvt if available, manual fallback ---------
#if defined(__has_builtin)
#if __has_builtin(__builtin_amdgcn_cvt_pk_f32_fp8) && __has_builtin(__builtin_amdgcn_cvt_pk_fp8_f32)
#define HAVE_FP8_HW 1
#endif
#endif

__device__ __forceinline__ uchar_t fp8_enc(float v) {
#ifdef HAVE_FP8_HW
    return (uchar_t)(__builtin_amdgcn_cvt_pk_fp8_f32(v, v, 0, false) & 0xff);
#else
    union { float f; uint_t u; } c; c.f = v;
    uint_t s = c.u >> 31;
    float av = fabsf(v);
    if (av > 448.f) av = 448.f;
    int e;
    float m = frexpf(av, &e);          // av = m * 2^e, m in [0.5,1)
    int ee = e + 6;                    // biased for e4m3 (bias 7, m in [1,2))
    uchar_t r;
    if (av == 0.f) r = 0;
    else if (ee <= 0) {                // denormal
        int q = (int)(av * 512.f + 0.5f);   // units of 2^-9
        if (q > 7) q = 7;
        r = (uchar_t)q;
    } else {
        int q = (int)(m * 16.f + 0.5f);     // m*16 in [8,16]
        if (q == 16) { q = 8; ee += 1; }
        if (ee > 15) { ee = 15; q = 15; }   // clamp toward max finite
        r = (uchar_t)((ee << 3) | (q & 7));
    }
    return r | (uchar_t)(s << 7);
#endif
}

__device__ __forceinline__ f2v_t fp8x2_dec_lo(uint_t w) {
#ifdef HAVE_FP8_HW
    return __builtin_amdgcn_cvt_pk_f32_fp8(w, false);
#else
    f2v_t r;
    for (int k = 0; k < 2; ++k) {
        uchar_t b = (w >> (8 * k)) & 0xff;
        uint_t s = (b >> 7) & 1, e = (b >> 3) & 15, m = b & 7;
        float f;
        if (e) { union { uint_t u; float ff; } c;
                 c.u = (s << 31) | ((e + 120) << 23) | (m << 20); f = c.ff; }
        else   { f = (float)m * 0.001953125f; if (s) f = -f; }
        r[k] = f;
    }
    return r;
#endif
}
__device__ __forceinline__ f2v_t fp8x2_dec_hi(uint_t w) {
#ifdef HAVE_FP8_HW
    return __builtin_amdgcn_cvt_pk_f32_fp8(w, true);
#else
    return fp8x2_dec_lo(w >> 16);
#endif
}

// ---------------------------------------------------------------------------
// CSR build, direct (no sort): zero -> atomic degree count -> 3-kernel scan
// -> atomic-cursor scatter. Every kernel has >=98 well-occupied blocks.
// ---------------------------------------------------------------------------
__global__ void zero_deg_kernel(int* __restrict__ deg) {
    int i = (blockIdx.x * 256 + threadIdx.x) * 4;
    if (i < N_NODES) *(int4*)(deg + i) = make_int4(0, 0, 0, 0);
}

__global__ void deg_count_kernel(const int* __restrict__ ei, int E,
                                 int* __restrict__ deg) {
    int e = blockIdx.x * blockDim.x + threadIdx.x;
    int step = gridDim.x * blockDim.x;
    for (; e < E; e += step)
        atomicAdd(&deg[ei[E + e]], 1);
}

// scan1: per-1024-block local exclusive scan of deg -> rowptr; block sums.
__global__ void scan1_kernel(const int* __restrict__ deg,
                             int* __restrict__ rowptr,
                             int* __restrict__ bsum) {
    __shared__ int ss[256];
    int b = blockIdx.x, t = threadIdx.x;
    int i0 = b * 1024 + t * 4;
    int4 d = make_int4(0, 0, 0, 0);
    if (i0 < N_NODES) d = *(const int4*)(deg + i0);   // N % 4 == 0
    int s = d.x + d.y + d.z + d.w;
    ss[t] = s;
    __syncthreads();
    for (int off = 1; off < 256; off <<= 1) {
        int u = (t >= off) ? ss[t - off] : 0;
        __syncthreads();
        ss[t] += u;
        __syncthreads();
    }
    int excl = ss[t] - s;
    if (t == 255) bsum[b] = ss[255];
    if (i0 < N_NODES) {
        int4 o;
        o.x = excl; o.y = excl + d.x; o.z = o.y + d.y; o.w = o.z + d.z;
        *(int4*)(rowptr + i0) = o;
    }
}

// scan2: single block scans the NS1 block sums; writes rowptr[N].
__global__ void scan2_kernel(const int* __restrict__ bsum,
                             int* __restrict__ bbase,
                             int* __restrict__ rowptr) {
    __shared__ int ss[128];
    int t = threadIdx.x;
    int v = (t < NS1) ? bsum[t] : 0;
    ss[t] = v;
    __syncthreads();
    for (int off = 1; off < 128; off <<= 1) {
        int u = (t >= off) ? ss[t - off] : 0;
        __syncthreads();
        ss[t] += u;
        __syncthreads();
    }
    if (t < NS1) bbase[t] = ss[t] - v;
    if (t == 127) rowptr[N_NODES] = ss[127];
}

// scan3: add block bases in place; also materialize the scatter cursor copy.
__global__ void scan3_kernel(int* __restrict__ rowptr,
                             const int* __restrict__ bbase,
                             int* __restrict__ cur) {
    int b = blockIdx.x, t = threadIdx.x;
    int i0 = b * 1024 + t * 4;
    if (i0 < N_NODES) {
        int base = bbase[b];
        int4 r = *(const int4*)(rowptr + i0);
        r.x += base; r.y += base; r.z += base; r.w += base;
        *(int4*)(rowptr + i0) = r;
        *(int4*)(cur + i0) = r;
    }
}

__global__ void scatter_csr_kernel(const int* __restrict__ ei, int E,
                                   int* __restrict__ cur,
                                   int* __restrict__ csr) {
    int e = blockIdx.x * blockDim.x + threadIdx.x;
    int step = gridDim.x * blockDim.x;
    for (; e < E; e += step) {
        int s = ei[e];
        int d = ei[E + e];
        int pos = atomicAdd(&cur[d], 1);
        csr[pos] = s;
    }
}

// ---------------------------------------------------------------------------
// cvt_w: bf16 [n][k]-major weight tensors.
// ---------------------------------------------------------------------------
__global__ void cvt_w_kernel(const float* __restrict__ W1l,
                             const float* __restrict__ W1r,
                             const float* __restrict__ W2l,
                             const float* __restrict__ W2r,
                             ushort_t* __restrict__ W1t,
                             ushort_t* __restrict__ W2t) {
    int t = blockIdx.x * blockDim.x + threadIdx.x;
    if (t < 128 * F_IN) {
        int n = t / F_IN, k = t - n * F_IN;
        float v = (n < HID) ? W1l[k * HID + n] : W1r[k * HID + (n - HID)];
        W1t[t] = f2b(v);
    } else if (t < 128 * F_IN + 80 * HID) {
        int u = t - 128 * F_IN;
        int n = u / HID, k = u - n * HID;
        float v = (n < N_CLS) ? W2l[k * N_CLS + n] : W2r[k * N_CLS + (n - N_CLS)];
        W2t[u] = f2b(v);
    }
}

// ---------------------------------------------------------------------------
// gemm1_mfma: y1(fp8, 64 B rows) | z1(bf16) = x @ [W1_l|W1_r].
// LDS-staged outputs, contiguous 16 B/lane stores.
// ---------------------------------------------------------------------------
__global__ void gemm1_mfma_kernel(const float* __restrict__ x,
                                  const ushort_t* __restrict__ W1t,
                                  uchar_t* __restrict__ y1f8,
                                  ushort_t* __restrict__ z1b) {
    __shared__ uchar_t sy[64][80];     // 5120 B, rows padded 64->80 (bank spread)
    __shared__ ushort_t sz[64][72];    // 9216 B, rows padded 64->72
    int tid = threadIdx.x;
    int wave = tid >> 6, lane = tid & 63;
    int tile = blockIdx.x * 4 + wave;
    int m0b = blockIdx.x * 64;
    if (tile < MT) {
        int m0 = tile * 16;
        int r = lane & 15, q = lane >> 4;
        const float* xr = x + (size_t)(m0 + r) * F_IN + q * 8;
        bf8_t a[4];
#pragma unroll
        for (int kt = 0; kt < 4; ++kt) {
            float4 u = *(const float4*)(xr + kt * 32);
            float4 v = *(const float4*)(xr + kt * 32 + 4);
            bf8_t tt;
            tt[0] = (short)f2b(u.x); tt[1] = (short)f2b(u.y);
            tt[2] = (short)f2b(u.z); tt[3] = (short)f2b(u.w);
            tt[4] = (short)f2b(v.x); tt[5] = (short)f2b(v.y);
            tt[6] = (short)f2b(v.z); tt[7] = (short)f2b(v.w);
            a[kt] = tt;
        }
        int lr0 = wave * 16 + q * 4;
#pragma unroll
        for (int tn = 0; tn < 8; ++tn) {
            const ushort_t* wr = W1t + (size_t)(tn * 16 + r) * F_IN + q * 8;
            f4_t acc = {0.f, 0.f, 0.f, 0.f};
#pragma unroll
            for (int kt = 0; kt < 4; ++kt) {
                bf8_t b = *(const bf8_t*)(wr + kt * 32);
                acc = __builtin_amdgcn_mfma_f32_16x16x32_bf16(a[kt], b, acc, 0, 0, 0);
            }
            int col = tn * 16 + r;
            if (col < 64) {
#pragma unroll
                for (int rr = 0; rr < 4; ++rr)
                    sy[lr0 + rr][col] = fp8_enc(acc[rr]);
            } else {
#pragma unroll
                for (int rr = 0; rr < 4; ++rr)
                    sz[lr0 + rr][col - 64] = f2b(acc[rr]);
            }
        }
    }
    __syncthreads();
    int vrows = N_NODES - m0b; if (vrows > 64) vrows = 64;
    for (int idx = tid; idx < vrows * 4; idx += 256) {
        int row = idx >> 2, c = (idx & 3) << 4;
        *(uint4*)(y1f8 + (size_t)(m0b + row) * 64 + c) = *(const uint4*)&sy[row][c];
    }
    for (int idx = tid; idx < vrows * 8; idx += 256) {
        int row = idx >> 3, c = (idx & 7) << 3;      // ushort offset, 8 = 16 B
        *(uint4*)(z1b + (size_t)(m0b + row) * HID + c) = *(const uint4*)&sz[row][c];
    }
}

// ---------------------------------------------------------------------------
// agg1: h = relu(mean y1[src] + b1 + z1).
// 4-lane group = one node (16 nodes/wave); lane l owns cols l*16..l*16+15 and
// fetches its 16-B quarter-row with ONE dwordx4. Unroll-4 => 4 independent
// row-gathers in flight per group (64 outstanding 16-B loads per wave).
// ---------------------------------------------------------------------------
__device__ __forceinline__ void acc16(float* acc, uint4 v) {
    f2v_t p;
    p = fp8x2_dec_lo(v.x); acc[0]  += p[0]; acc[1]  += p[1];
    p = fp8x2_dec_hi(v.x); acc[2]  += p[0]; acc[3]  += p[1];
    p = fp8x2_dec_lo(v.y); acc[4]  += p[0]; acc[5]  += p[1];
    p = fp8x2_dec_hi(v.y); acc[6]  += p[0]; acc[7]  += p[1];
    p = fp8x2_dec_lo(v.z); acc[8]  += p[0]; acc[9]  += p[1];
    p = fp8x2_dec_hi(v.z); acc[10] += p[0]; acc[11] += p[1];
    p = fp8x2_dec_lo(v.w); acc[12] += p[0]; acc[13] += p[1];
    p = fp8x2_dec_hi(v.w); acc[14] += p[0]; acc[15] += p[1];
}

__global__ void agg1_kernel(const int* __restrict__ rowptr,
                            const int* __restrict__ csr,
                            const uchar_t* __restrict__ y1f8,
                            const ushort_t* __restrict__ z1b,
                            const float* __restrict__ b1,
                            ushort_t* __restrict__ hb) {
    int gid = blockIdx.x * blockDim.x + threadIdx.x;
    int wave = gid >> 6, lane = gid & 63;
    int g = lane >> 2, l = lane & 3;
    int n = wave * 16 + g;                // N_NODES % 16 == 0
    if (n >= N_NODES) return;
    int beg = rowptr[n], end = rowptr[n + 1];
    float acc[16];
#pragma unroll
    for (int j = 0; j < 16; ++j) acc[j] = 0.f;
    const uchar_t* yb = y1f8 + l * 16;
    int i = beg;
    for (; i + 3 < end; i += 4) {
        int s0 = csr[i], s1 = csr[i + 1], s2 = csr[i + 2], s3 = csr[i + 3];
        uint4 w0 = *(const uint4*)(yb + (size_t)s0 * 64);
        uint4 w1 = *(const uint4*)(yb + (size_t)s1 * 64);
        uint4 w2 = *(const uint4*)(yb + (size_t)s2 * 64);
        uint4 w3 = *(const uint4*)(yb + (size_t)s3 * 64);
        acc16(acc, w0); acc16(acc, w1); acc16(acc, w2); acc16(acc, w3);
    }
    for (; i < end; ++i) {
        uint4 w = *(const uint4*)(yb + (size_t)csr[i] * 64);
        acc16(acc, w);
    }
    float inv = 1.0f / fmaxf((float)(end - beg), 1.0f);
    int c = l * 16;
    ushort_t zz[16];
    *(uint4*)&zz[0] = *(const uint4*)(z1b + (size_t)n * HID + c);
    *(uint4*)&zz[8] = *(const uint4*)(z1b + (size_t)n * HID + c + 8);
    float bv[16];
    *(float4*)&bv[0]  = *(const float4*)(b1 + c);
    *(float4*)&bv[4]  = *(const float4*)(b1 + c + 4);
    *(float4*)&bv[8]  = *(const float4*)(b1 + c + 8);
    *(float4*)&bv[12] = *(const float4*)(b1 + c + 12);
    ushort_t o[16];
#pragma unroll
    for (int j = 0; j < 16; ++j) {
        float r = fmaxf(fmaf(acc[j], inv, bv[j] + b2f(zz[j])), 0.f);
        o[j] = f2b(r);
    }
    *(uint4*)(hb + (size_t)n * HID + c)     = *(const uint4*)&o[0];
    *(uint4*)(hb + (size_t)n * HID + c + 8) = *(const uint4*)&o[8];
}

// ---------------------------------------------------------------------------
// gemm2_mfma: y2(fp8, 40 B packed rows) | z2(bf16, stride 64) = h @ [W2l|W2r].
// LDS-staged outputs, contiguous wide stores (y2 block region = 2560 B flat).
// ---------------------------------------------------------------------------
__global__ void gemm2_mfma_kernel(const ushort_t* __restrict__ hb,
                                  const ushort_t* __restrict__ W2t,
                                  uchar_t* __restrict__ y2f8,
                                  ushort_t* __restrict__ z2b) {
    __shared__ uchar_t sy2[64 * 40];    // 2560 B flat (block y2 region image)
    __shared__ ushort_t sz2[64][56];    // 7168 B, rows padded 40->56
    int tid = threadIdx.x;
    int wave = tid >> 6, lane = tid & 63;
    int tile = blockIdx.x * 4 + wave;
    int m0b = blockIdx.x * 64;
    if (tile < MT) {
        int m0 = tile * 16;
        int r = lane & 15, q = lane >> 4;
        const ushort_t* hr = hb + (size_t)(m0 + r) * HID + q * 8;
        bf8_t a[2];
#pragma unroll
        for (int kt = 0; kt < 2; ++kt)
            a[kt] = *(const bf8_t*)(hr + kt * 32);
        int lr0 = wave * 16 + q * 4;
#pragma unroll
        for (int tn = 0; tn < 5; ++tn) {
            const ushort_t* wr = W2t + (size_t)(tn * 16 + r) * HID + q * 8;
            f4_t acc = {0.f, 0.f, 0.f, 0.f};
#pragma unroll
            for (int kt = 0; kt < 2; ++kt) {
                bf8_t b = *(const bf8_t*)(wr + kt * 32);
                acc = __builtin_amdgcn_mfma_f32_16x16x32_bf16(a[kt], b, acc, 0, 0, 0);
            }
            int col = tn * 16 + r;
            if (col < N_CLS) {
#pragma unroll
                for (int rr = 0; rr < 4; ++rr)
                    sy2[(lr0 + rr) * 40 + col] = fp8_enc(acc[rr]);
            } else {
#pragma unroll
                for (int rr = 0; rr < 4; ++rr)
                    sz2[lr0 + rr][col - N_CLS] = f2b(acc[rr]);
            }
        }
    }
    __syncthreads();
    int vrows = N_NODES - m0b; if (vrows > 64) vrows = 64;
    int nch = (vrows * 40) >> 4;        // 16 B chunks; vrows*40 divisible by 16
    for (int idx = tid; idx < nch; idx += 256)
        *(uint4*)(y2f8 + (size_t)m0b * 40 + idx * 16) = *(const uint4*)&sy2[idx * 16];
    for (int idx = tid; idx < vrows * 5; idx += 256) {
        int row = idx / 5, c = (idx - row * 5) * 8;   // ushorts; 8 = 16 B
        *(uint4*)(z2b + (size_t)(m0b + row) * HID + c) = *(const uint4*)&sz2[row][c];
    }
}

// ---------------------------------------------------------------------------
// agg2 + log_softmax. One 16-lane group = one node; y2 rows are 40 B packed.
// Gather predicated under l<10 (exec-masked lanes issue no VMEM traffic).
// Unroll-8 with batched index loads for deeper MLP.
// ---------------------------------------------------------------------------
__global__ void agg2_kernel(const int* __restrict__ rowptr,
                            const int* __restrict__ csr,
                            const uchar_t* __restrict__ y2f8,
                            const ushort_t* __restrict__ z2b,
                            const float* __restrict__ b2,
                            float* __restrict__ out) {
    int gid = blockIdx.x * blockDim.x + threadIdx.x;
    int wave = gid >> 6, lane = gid & 63;
    int g = lane >> 4, l = lane & 15;
    int n = wave * 4 + g;
    if (n >= N_NODES) return;
    int beg = rowptr[n], end = rowptr[n + 1];
    float a0 = 0.f, a1 = 0.f, a2 = 0.f, a3 = 0.f;
    float4 bb = make_float4(0.f, 0.f, 0.f, 0.f);
    ushort4 zz; zz.x = 0; zz.y = 0; zz.z = 0; zz.w = 0;
    int c0 = l * 4;
    if (l < 10) {
        int i = beg;
        for (; i + 7 < end; i += 8) {
            int s0 = csr[i],     s1 = csr[i + 1], s2 = csr[i + 2], s3 = csr[i + 3];
            int s4 = csr[i + 4], s5 = csr[i + 5], s6 = csr[i + 6], s7 = csr[i + 7];
            uint_t w0 = *(const uint_t*)(y2f8 + (size_t)s0 * 40 + c0);
            uint_t w1 = *(const uint_t*)(y2f8 + (size_t)s1 * 40 + c0);
            uint_t w2 = *(const uint_t*)(y2f8 + (size_t)s2 * 40 + c0);
            uint_t w3 = *(const uint_t*)(y2f8 + (size_t)s3 * 40 + c0);
            uint_t w4 = *(const uint_t*)(y2f8 + (size_t)s4 * 40 + c0);
            uint_t w5 = *(const uint_t*)(y2f8 + (size_t)s5 * 40 + c0);
            uint_t w6 = *(const uint_t*)(y2f8 + (size_t)s6 * 40 + c0);
            uint_t w7 = *(const uint_t*)(y2f8 + (size_t)s7 * 40 + c0);
            f2v_t p;
            p = fp8x2_dec_lo(w0); a0 += p[0]; a1 += p[1];
            p = fp8x2_dec_hi(w0); a2 += p[0]; a3 += p[1];
            p = fp8x2_dec_lo(w1); a0 += p[0]; a1 += p[1];
            p = fp8x2_dec_hi(w1); a2 += p[0]; a3 += p[1];
            p = fp8x2_dec_lo(w2); a0 += p[0]; a1 += p[1];
            p = fp8x2_dec_hi(w2); a2 += p[0]; a3 += p[1];
            p = fp8x2_dec_lo(w3); a0 += p[0]; a1 += p[1];
            p = fp8x2_dec_hi(w3); a2 += p[0]; a3 += p[1];
            p = fp8x2_dec_lo(w4); a0 += p[0]; a1 += p[1];
            p = fp8x2_dec_hi(w4); a2 += p[0]; a3 += p[1];
            p = fp8x2_dec_lo(w5); a0 += p[0]; a1 += p[1];
            p = fp8x2_dec_hi(w5); a2 += p[0]; a3 += p[1];
            p = fp8x2_dec_lo(w6); a0 += p[0]; a1 += p[1];
            p = fp8x2_dec_hi(w6); a2 += p[0]; a3 += p[1];
            p = fp8x2_dec_lo(w7); a0 += p[0]; a1 += p[1];
            p = fp8x2_dec_hi(w7); a2 += p[0]; a3 += p[1];
        }
        for (; i + 3 < end; i += 4) {
            int s0 = csr[i], s1 = csr[i + 1], s2 = csr[i + 2], s3 = csr[i + 3];
            uint_t w0 = *(const uint_t*)(y2f8 + (size_t)s0 * 40 + c0);
            uint_t w1 = *(const uint_t*)(y2f8 + (size_t)s1 * 40 + c0);
            uint_t w2 = *(const uint_t*)(y2f8 + (size_t)s2 * 40 + c0);
            uint_t w3 = *(const uint_t*)(y2f8 + (size_t)s3 * 40 + c0);
            f2v_t p;
            p = fp8x2_dec_lo(w0); a0 += p[0]; a1 += p[1];
            p = fp8x2_dec_hi(w0); a2 += p[0]; a3 += p[1];
            p = fp8x2_dec_lo(w1); a0 += p[0]; a1 += p[1];
            p = fp8x2_dec_hi(w1); a2 += p[0]; a3 += p[1];
            p = fp8x2_dec_lo(w2); a0 += p[0]; a1 += p[1];
            p = fp8x2_dec_hi(w2); a2 += p[0]; a3 += p[1];
            p = fp8x2_dec_lo(w3); a0 += p[0]; a1 += p[1];
            p = fp8x2_dec_hi(w3); a2 += p[0]; a3 += p[1];
        }
        for (; i < end; ++i) {
            uint_t w = *(const uint_t*)(y2f8 + (size_t)csr[i] * 40 + c0);
            f2v_t p0 = fp8x2_dec_lo(w), p1 = fp8x2_dec_hi(w);
            a0 += p0[0]; a1 += p0[1]; a2 += p1[0]; a3 += p1[1];
        }
        bb = *(const float4*)(b2 + c0);
        zz = *(const ushort4*)(z2b + (size_t)n * HID + c0);
    }
    float inv = 1.0f / fmaxf((float)(end - beg), 1.0f);
    float v0 = (c0 + 0 < N_CLS) ? fmaf(a0, inv, bb.x + b2f(zz.x)) : -INFINITY;
    float v1 = (c0 + 1 < N_CLS) ? fmaf(a1, inv, bb.y + b2f(zz.y)) : -INFINITY;
    float v2 = (c0 + 2 < N_CLS) ? fmaf(a2, inv, bb.z + b2f(zz.z)) : -INFINITY;
    float v3 = (c0 + 3 < N_CLS) ? fmaf(a3, inv, bb.w + b2f(zz.w)) : -INFINITY;

    float m = fmaxf(fmaxf(v0, v1), fmaxf(v2, v3));
#pragma unroll
    for (int off = 1; off < 16; off <<= 1)
        m = fmaxf(m, __shfl_xor(m, off, 64));
    float s = 0.f;
    if (v0 > -INFINITY) s += expf(v0 - m);
    if (v1 > -INFINITY) s += expf(v1 - m);
    if (v2 > -INFINITY) s += expf(v2 - m);
    if (v3 > -INFINITY) s += expf(v3 - m);
#pragma unroll
    for (int off = 1; off < 16; off <<= 1)
        s += __shfl_xor(s, off, 64);
    float ls = logf(s);
    if (l < 10) {
        float4 o = make_float4(v0 - m - ls, v1 - m - ls, v2 - m - ls, v3 - m - ls);
        *(float4*)(out + (size_t)n * N_CLS + c0) = o;
    }
}

extern "C" void kernel_launch(void* const* d_in, const int* in_sizes, int n_in,
                              void* d_out, int out_size, void* d_ws, size_t ws_size,
                              hipStream_t stream) {
    const float* x   = (const float*)d_in[0];
    const int*   ei  = (const int*)d_in[1];
    const float* W1l = (const float*)d_in[2];
    const float* b1  = (const float*)d_in[3];
    const float* W1r = (const float*)d_in[4];
    const float* W2l = (const float*)d_in[5];
    const float* b2  = (const float*)d_in[6];
    const float* W2r = (const float*)d_in[7];
    float* out = (float*)d_out;
    const int E = in_sizes[1] / 2;

    char* p = (char*)d_ws;
    auto take = [&](size_t bytes) {
        char* q = p;
        p += (bytes + 15) & ~(size_t)15;
        return (void*)q;
    };
    int* rowptr     = (int*)take(sizeof(int) * (N_NODES + 4));
    int* deg        = (int*)take(sizeof(int) * N_NODES);
    int* cur        = (int*)take(sizeof(int) * N_NODES);
    int* bsum       = (int*)take(sizeof(int) * 128);
    int* bbase      = (int*)take(sizeof(int) * 128);
    int* csr        = (int*)take(sizeof(int) * (size_t)E);
    ushort_t* W1t   = (ushort_t*)take(sizeof(ushort_t) * 128 * F_IN);
    ushort_t* W2t   = (ushort_t*)take(sizeof(ushort_t) * 80 * HID);
    uchar_t* y1f8   = (uchar_t*)take(sizeof(uchar_t) * (size_t)N_NODES * 64);
    ushort_t* z1b   = (ushort_t*)take(sizeof(ushort_t) * (size_t)N_NODES * HID);
    ushort_t* hb    = (ushort_t*)take(sizeof(ushort_t) * (size_t)N_NODES * HID);
    // y1f8 is 6.4 MB, dead after agg1: reuse for y2 (N*40 = 4.0 MB).
    uchar_t* y2f8 = y1f8;
    ushort_t* z2b = z1b;    // dead after agg1; stride-64 rows, 40 real cols

    const int B = 256;

    zero_deg_kernel<<<NS1, B, 0, stream>>>(deg);
    deg_count_kernel<<<1024, B, 0, stream>>>(ei, E, deg);
    scan1_kernel<<<NS1, B, 0, stream>>>(deg, rowptr, bsum);
    scan2_kernel<<<1, 128, 0, stream>>>(bsum, bbase, rowptr);
    scan3_kernel<<<NS1, B, 0, stream>>>(rowptr, bbase, cur);
    scatter_csr_kernel<<<1024, B, 0, stream>>>(ei, E, cur, csr);

    cvt_w_kernel<<<(128 * F_IN + 80 * HID + B - 1) / B, B, 0, stream>>>(
        W1l, W1r, W2l, W2r, W1t, W2t);

    int gemm_blocks = (MT + 3) / 4;     // 4 tiles (64 rows) per block
    int t_agg1 = (N_NODES / 16) * 64;   // 16 nodes per wave (4-lane groups)
    int t_agg2 = (N_NODES / 4) * 64;    // 4 nodes per wave (16-lane groups)

    gemm1_mfma_kernel<<<gemm_blocks, B, 0, stream>>>(x, W1t, y1f8, z1b);
    agg1_kernel<<<(t_agg1 + B - 1) / B, B, 0, stream>>>(rowptr, csr, y1f8, z1b, b1, hb);
    gemm2_mfma_kernel<<<gemm_blocks, B, 0, stream>>>(hb, W2t, y2f8, z2b);
    agg2_kernel<<<(t_agg2 + B - 1) / B, B, 0, stream>>>(rowptr, csr, y2f8, z2b, b2, out);
}

// Round 6
// 246.410 us; speedup vs baseline: 1.6270x; 1.6270x over previous
//
#include <hip/hip_runtime.h>
#include <math.h>

#define N_NODES 100000
#define F_IN    128
#define HID     64
#define N_CLS   40
#define MT      (N_NODES / 16)                  // 6250 M-tiles of 16 nodes

#define BSHIFT  9
#define BSZ     512                              // dsts per coarse bucket
#define NB      ((N_NODES + BSZ - 1) / BSZ)      // 196 buckets
#define EPB     4096                             // edges per block in sort passes

typedef __attribute__((ext_vector_type(8))) short bf8_t;   // 8 bf16 (4 VGPR)
typedef __attribute__((ext_vector_type(4))) float f4_t;    // MFMA C/D frag
typedef __attribute__((ext_vector_type(2))) float f2v_t;

typedef unsigned short ushort_t;
typedef unsigned int uint_t;
typedef unsigned char uchar_t;

__device__ __forceinline__ ushort_t f2b(float f) {   // f32 -> bf16 RNE
    union { float f; uint_t u; } c; c.f = f;
    uint_t u = c.u + 0x7FFFu + ((c.u >> 16) & 1u);
    return (ushort_t)(u >> 16);
}
__device__ __forceinline__ float b2f(ushort_t h) {
    union { uint_t u; float f; } c; c.u = ((uint_t)h) << 16;
    return c.f;
}

// ---- fp8 e4m3 (OCP) helpers: HW cvt if available, manual fallback ---------
#if defined(__has_builtin)
#if __has_builtin(__builtin_amdgcn_cvt_pk_f32_fp8) && __has_builtin(__builtin_amdgcn_cvt_pk_fp8_f32)
#define HAVE_FP8_HW 1
#endif
#endif

__device__ __forceinline__ uchar_t fp8_enc(float v) {
#ifdef HAVE_FP8_HW
    return (uchar_t)(__builtin_amdgcn_cvt_pk_fp8_f32(v, v, 0, false) & 0xff);
#else
    union { float f; uint_t u; } c; c.f = v;
    uint_t s = c.u >> 31;
    float av = fabsf(v);
    if (av > 448.f) av = 448.f;
    int e;
    float m = frexpf(av, &e);          // av = m * 2^e, m in [0.5,1)
    int ee = e + 6;                    // biased for e4m3 (bias 7, m in [1,2))
    uchar_t r;
    if (av == 0.f) r = 0;
    else if (ee <= 0) {                // denormal
        int q = (int)(av * 512.f + 0.5f);   // units of 2^-9
        if (q > 7) q = 7;
        r = (uchar_t)q;
    } else {
        int q = (int)(m * 16.f + 0.5f);     // m*16 in [8,16]
        if (q == 16) { q = 8; ee += 1; }
        if (ee > 15) { ee = 15; q = 15; }   // clamp toward max finite
        r = (uchar_t)((ee << 3) | (q & 7));
    }
    return r | (uchar_t)(s << 7);
#endif
}

__device__ __forceinline__ f2v_t fp8x2_dec_lo(uint_t w) {
#ifdef HAVE_FP8_HW
    return __builtin_amdgcn_cvt_pk_f32_fp8(w, false);
#else
    f2v_t r;
    for (int k = 0; k < 2; ++k) {
        uchar_t b = (w >> (8 * k)) & 0xff;
        uint_t s = (b >> 7) & 1, e = (b >> 3) & 15, m = b & 7;
        float f;
        if (e) { union { uint_t u; float ff; } c;
                 c.u = (s << 31) | ((e + 120) << 23) | (m << 20); f = c.ff; }
        else   { f = (float)m * 0.001953125f; if (s) f = -f; }
        r[k] = f;
    }
    return r;
#endif
}
__device__ __forceinline__ f2v_t fp8x2_dec_hi(uint_t w) {
#ifdef HAVE_FP8_HW
    return __builtin_amdgcn_cvt_pk_f32_fp8(w, true);
#else
    return fp8x2_dec_lo(w >> 16);
#endif
}

// ---------------------------------------------------------------------------
// Sort pass 1: per-block LDS histogram over 196 coarse buckets (dst >> 9).
// ---------------------------------------------------------------------------
__global__ void block_hist_kernel(const int* __restrict__ ei, int E,
                                  int* __restrict__ blockHist) {
    __shared__ int cnt[NB];
    int t = threadIdx.x, blk = blockIdx.x;
    for (int i = t; i < NB; i += 256) cnt[i] = 0;
    __syncthreads();
    int e0 = blk * EPB;
#pragma unroll
    for (int i = 0; i < EPB / 256; ++i) {
        int e = e0 + i * 256 + t;
        if (e < E) atomicAdd(&cnt[ei[E + e] >> BSHIFT], 1);
    }
    __syncthreads();
    for (int i = t; i < NB; i += 256) blockHist[blk * NB + i] = cnt[i];
}

// ---------------------------------------------------------------------------
// Sort pass 2: per-bin exclusive scan down the blocks.
// ---------------------------------------------------------------------------
__global__ void col_scan_kernel(const int* __restrict__ blockHist, int nblk,
                                int* __restrict__ blockBase,
                                int* __restrict__ btot) {
    __shared__ int ss[256];
    __shared__ int carry;
    int bin = blockIdx.x, t = threadIdx.x;
    if (t == 0) carry = 0;
    __syncthreads();
    for (int c0 = 0; c0 < nblk; c0 += 256) {
        int b = c0 + t;
        int v = (b < nblk) ? blockHist[b * NB + bin] : 0;
        ss[t] = v;
        __syncthreads();
        for (int off = 1; off < 256; off <<= 1) {
            int u = (t >= off) ? ss[t - off] : 0;
            __syncthreads();
            ss[t] += u;
            __syncthreads();
        }
        if (b < nblk) blockBase[b * NB + bin] = carry + ss[t] - v;
        __syncthreads();
        if (t == 255) carry += ss[255];
        __syncthreads();
    }
    if (t == 0) btot[bin] = carry;
}

// ---------------------------------------------------------------------------
// Sort pass 3: scatter packed (src<<9 | dst&511) into coarse-bucket order.
// Bucket base offsets computed locally from btot (196-elem LDS scan).
// ---------------------------------------------------------------------------
__global__ void scatter_pairs_kernel(const int* __restrict__ ei, int E,
                                     const int* __restrict__ blockBase,
                                     const int* __restrict__ btot,
                                     uint_t* __restrict__ pairs) {
    __shared__ int cur[NB];
    __shared__ int base[NB];
    __shared__ int ss[256];
    int t = threadIdx.x, blk = blockIdx.x;
    int v = (t < NB) ? btot[t] : 0;
    ss[t] = v;
    __syncthreads();
    for (int off = 1; off < 256; off <<= 1) {
        int u = (t >= off) ? ss[t - off] : 0;
        __syncthreads();
        ss[t] += u;
        __syncthreads();
    }
    if (t < NB) {
        cur[t] = 0;
        base[t] = (ss[t] - v) + blockBase[blk * NB + t];
    }
    __syncthreads();
    int e0 = blk * EPB;
#pragma unroll
    for (int i = 0; i < EPB / 256; ++i) {
        int e = e0 + i * 256 + t;
        if (e < E) {
            int src = ei[e];
            int dst = ei[E + e];
            int bin = dst >> BSHIFT;
            int r = atomicAdd(&cur[bin], 1);   // LDS atomic
            pairs[base[bin] + r] = ((uint_t)src << BSHIFT) | (uint_t)(dst & (BSZ - 1));
        }
    }
}

// ---------------------------------------------------------------------------
// Sort pass 4: per-bucket fine sort. Bucket base computed locally
// from btot; rowptr + contiguous csr region; rowptr[N] written by last bin.
// ---------------------------------------------------------------------------
__global__ void bucket_sort_kernel(const uint_t* __restrict__ pairs,
                                   const int* __restrict__ btot,
                                   int* __restrict__ rowptr,
                                   int* __restrict__ csr) {
    __shared__ int hist[BSZ];
    __shared__ int lofs[BSZ];
    int bin = blockIdx.x, t = threadIdx.x;
    // local exclusive prefix of btot over 196 bins (inclusive scan, then shift)
    int pv = (t < NB) ? btot[t] : 0;
    lofs[t] = pv;
    __syncthreads();
    for (int off = 1; off < BSZ; off <<= 1) {
        int u = (t >= off) ? lofs[t - off] : 0;
        __syncthreads();
        lofs[t] += u;
        __syncthreads();
    }
    int base = (bin > 0) ? lofs[bin - 1] : 0;   // broadcast LDS read
    int cnt = btot[bin];
    __syncthreads();
    hist[t] = 0;
    __syncthreads();
    for (int i = t; i < cnt; i += BSZ)
        atomicAdd(&hist[pairs[base + i] & (BSZ - 1)], 1);
    __syncthreads();
    int v = hist[t];
    lofs[t] = v;
    __syncthreads();
    for (int off = 1; off < BSZ; off <<= 1) {
        int u = (t >= off) ? lofs[t - off] : 0;
        __syncthreads();
        lofs[t] += u;
        __syncthreads();
    }
    int excl = lofs[t] - v;
    int d_global = (bin << BSHIFT) + t;
    if (d_global < N_NODES) rowptr[d_global] = base + excl;
    if (bin == NB - 1 && t == 0) rowptr[N_NODES] = base + cnt;
    __syncthreads();
    lofs[t] = excl;
    hist[t] = 0;
    __syncthreads();
    for (int i = t; i < cnt; i += BSZ) {
        uint_t p = pairs[base + i];
        int lb = p & (BSZ - 1);
        int r = atomicAdd(&hist[lb], 1);
        csr[base + lofs[lb] + r] = (int)(p >> BSHIFT);
    }
}

// ---------------------------------------------------------------------------
// cvt_w: bf16 [n][k]-major weight tensors.
// ---------------------------------------------------------------------------
__global__ void cvt_w_kernel(const float* __restrict__ W1l,
                             const float* __restrict__ W1r,
                             const float* __restrict__ W2l,
                             const float* __restrict__ W2r,
                             ushort_t* __restrict__ W1t,
                             ushort_t* __restrict__ W2t) {
    int t = blockIdx.x * blockDim.x + threadIdx.x;
    if (t < 128 * F_IN) {
        int n = t / F_IN, k = t - n * F_IN;
        float v = (n < HID) ? W1l[k * HID + n] : W1r[k * HID + (n - HID)];
        W1t[t] = f2b(v);
    } else if (t < 128 * F_IN + 80 * HID) {
        int u = t - 128 * F_IN;
        int n = u / HID, k = u - n * HID;
        float v = (n < N_CLS) ? W2l[k * N_CLS + n] : W2r[k * N_CLS + (n - N_CLS)];
        W2t[u] = f2b(v);
    }
}

// ---------------------------------------------------------------------------
// gemm1_mfma: y1(fp8, 64 B rows) | z1(bf16) = x @ [W1_l|W1_r].
// LDS-staged outputs, contiguous 16 B/lane stores.
// ---------------------------------------------------------------------------
__global__ void gemm1_mfma_kernel(const float* __restrict__ x,
                                  const ushort_t* __restrict__ W1t,
                                  uchar_t* __restrict__ y1f8,
                                  ushort_t* __restrict__ z1b) {
    __shared__ uchar_t sy[64][80];     // 5120 B, rows padded 64->80 (bank spread)
    __shared__ ushort_t sz[64][72];    // 9216 B, rows padded 64->72
    int tid = threadIdx.x;
    int wave = tid >> 6, lane = tid & 63;
    int tile = blockIdx.x * 4 + wave;
    int m0b = blockIdx.x * 64;
    if (tile < MT) {
        int m0 = tile * 16;
        int r = lane & 15, q = lane >> 4;
        const float* xr = x + (size_t)(m0 + r) * F_IN + q * 8;
        bf8_t a[4];
#pragma unroll
        for (int kt = 0; kt < 4; ++kt) {
            float4 u = *(const float4*)(xr + kt * 32);
            float4 v = *(const float4*)(xr + kt * 32 + 4);
            bf8_t tt;
            tt[0] = (short)f2b(u.x); tt[1] = (short)f2b(u.y);
            tt[2] = (short)f2b(u.z); tt[3] = (short)f2b(u.w);
            tt[4] = (short)f2b(v.x); tt[5] = (short)f2b(v.y);
            tt[6] = (short)f2b(v.z); tt[7] = (short)f2b(v.w);
            a[kt] = tt;
        }
        int lr0 = wave * 16 + q * 4;
#pragma unroll
        for (int tn = 0; tn < 8; ++tn) {
            const ushort_t* wr = W1t + (size_t)(tn * 16 + r) * F_IN + q * 8;
            f4_t acc = {0.f, 0.f, 0.f, 0.f};
#pragma unroll
            for (int kt = 0; kt < 4; ++kt) {
                bf8_t b = *(const bf8_t*)(wr + kt * 32);
                acc = __builtin_amdgcn_mfma_f32_16x16x32_bf16(a[kt], b, acc, 0, 0, 0);
            }
            int col = tn * 16 + r;
            if (col < 64) {
#pragma unroll
                for (int rr = 0; rr < 4; ++rr)
                    sy[lr0 + rr][col] = fp8_enc(acc[rr]);
            } else {
#pragma unroll
                for (int rr = 0; rr < 4; ++rr)
                    sz[lr0 + rr][col - 64] = f2b(acc[rr]);
            }
        }
    }
    __syncthreads();
    int vrows = N_NODES - m0b; if (vrows > 64) vrows = 64;
    for (int idx = tid; idx < vrows * 4; idx += 256) {
        int row = idx >> 2, c = (idx & 3) << 4;
        *(uint4*)(y1f8 + (size_t)(m0b + row) * 64 + c) = *(const uint4*)&sy[row][c];
    }
    for (int idx = tid; idx < vrows * 8; idx += 256) {
        int row = idx >> 3, c = (idx & 7) << 3;      // ushort offset, 8 = 16 B
        *(uint4*)(z1b + (size_t)(m0b + row) * HID + c) = *(const uint4*)&sz[row][c];
    }
}

// ---------------------------------------------------------------------------
// agg1: h = relu(mean y1[src] + b1 + z1).
// 4-lane group = one node (16 nodes/wave); lane l owns cols l*16..l*16+15 and
// fetches its 16-B quarter-row with ONE dwordx4. Unroll-4 => 4 independent
// row-gathers in flight per group (64 outstanding 16-B loads per wave).
// ---------------------------------------------------------------------------
__device__ __forceinline__ void acc16(float* acc, uint4 v) {
    f2v_t p;
    p = fp8x2_dec_lo(v.x); acc[0]  += p[0]; acc[1]  += p[1];
    p = fp8x2_dec_hi(v.x); acc[2]  += p[0]; acc[3]  += p[1];
    p = fp8x2_dec_lo(v.y); acc[4]  += p[0]; acc[5]  += p[1];
    p = fp8x2_dec_hi(v.y); acc[6]  += p[0]; acc[7]  += p[1];
    p = fp8x2_dec_lo(v.z); acc[8]  += p[0]; acc[9]  += p[1];
    p = fp8x2_dec_hi(v.z); acc[10] += p[0]; acc[11] += p[1];
    p = fp8x2_dec_lo(v.w); acc[12] += p[0]; acc[13] += p[1];
    p = fp8x2_dec_hi(v.w); acc[14] += p[0]; acc[15] += p[1];
}

__global__ void agg1_kernel(const int* __restrict__ rowptr,
                            const int* __restrict__ csr,
                            const uchar_t* __restrict__ y1f8,
                            const ushort_t* __restrict__ z1b,
                            const float* __restrict__ b1,
                            ushort_t* __restrict__ hb) {
    int gid = blockIdx.x * blockDim.x + threadIdx.x;
    int wave = gid >> 6, lane = gid & 63;
    int g = lane >> 2, l = lane & 3;
    int n = wave * 16 + g;                // N_NODES % 16 == 0
    if (n >= N_NODES) return;
    int beg = rowptr[n], end = rowptr[n + 1];
    float acc[16];
#pragma unroll
    for (int j = 0; j < 16; ++j) acc[j] = 0.f;
    const uchar_t* yb = y1f8 + l * 16;
    int i = beg;
    for (; i + 3 < end; i += 4) {
        int s0 = csr[i], s1 = csr[i + 1], s2 = csr[i + 2], s3 = csr[i + 3];
        uint4 w0 = *(const uint4*)(yb + (size_t)s0 * 64);
        uint4 w1 = *(const uint4*)(yb + (size_t)s1 * 64);
        uint4 w2 = *(const uint4*)(yb + (size_t)s2 * 64);
        uint4 w3 = *(const uint4*)(yb + (size_t)s3 * 64);
        acc16(acc, w0); acc16(acc, w1); acc16(acc, w2); acc16(acc, w3);
    }
    for (; i < end; ++i) {
        uint4 w = *(const uint4*)(yb + (size_t)csr[i] * 64);
        acc16(acc, w);
    }
    float inv = 1.0f / fmaxf((float)(end - beg), 1.0f);
    int c = l * 16;
    ushort_t zz[16];
    *(uint4*)&zz[0] = *(const uint4*)(z1b + (size_t)n * HID + c);
    *(uint4*)&zz[8] = *(const uint4*)(z1b + (size_t)n * HID + c + 8);
    float bv[16];
    *(float4*)&bv[0]  = *(const float4*)(b1 + c);
    *(float4*)&bv[4]  = *(const float4*)(b1 + c + 4);
    *(float4*)&bv[8]  = *(const float4*)(b1 + c + 8);
    *(float4*)&bv[12] = *(const float4*)(b1 + c + 12);
    ushort_t o[16];
#pragma unroll
    for (int j = 0; j < 16; ++j) {
        float r = fmaxf(fmaf(acc[j], inv, bv[j] + b2f(zz[j])), 0.f);
        o[j] = f2b(r);
    }
    *(uint4*)(hb + (size_t)n * HID + c)     = *(const uint4*)&o[0];
    *(uint4*)(hb + (size_t)n * HID + c + 8) = *(const uint4*)&o[8];
}

// ---------------------------------------------------------------------------
// gemm2_mfma: y2(fp8, 40 B packed rows) | z2(bf16, stride 64) = h @ [W2l|W2r].
// LDS-staged outputs, contiguous wide stores (y2 block region = 2560 B flat).
// ---------------------------------------------------------------------------
__global__ void gemm2_mfma_kernel(const ushort_t* __restrict__ hb,
                                  const ushort_t* __restrict__ W2t,
                                  uchar_t* __restrict__ y2f8,
                                  ushort_t* __restrict__ z2b) {
    __shared__ uchar_t sy2[64 * 40];    // 2560 B flat (block y2 region image)
    __shared__ ushort_t sz2[64][56];    // 7168 B, rows padded 40->56
    int tid = threadIdx.x;
    int wave = tid >> 6, lane = tid & 63;
    int tile = blockIdx.x * 4 + wave;
    int m0b = blockIdx.x * 64;
    if (tile < MT) {
        int m0 = tile * 16;
        int r = lane & 15, q = lane >> 4;
        const ushort_t* hr = hb + (size_t)(m0 + r) * HID + q * 8;
        bf8_t a[2];
#pragma unroll
        for (int kt = 0; kt < 2; ++kt)
            a[kt] = *(const bf8_t*)(hr + kt * 32);
        int lr0 = wave * 16 + q * 4;
#pragma unroll
        for (int tn = 0; tn < 5; ++tn) {
            const ushort_t* wr = W2t + (size_t)(tn * 16 + r) * HID + q * 8;
            f4_t acc = {0.f, 0.f, 0.f, 0.f};
#pragma unroll
            for (int kt = 0; kt < 2; ++kt) {
                bf8_t b = *(const bf8_t*)(wr + kt * 32);
                acc = __builtin_amdgcn_mfma_f32_16x16x32_bf16(a[kt], b, acc, 0, 0, 0);
            }
            int col = tn * 16 + r;
            if (col < N_CLS) {
#pragma unroll
                for (int rr = 0; rr < 4; ++rr)
                    sy2[(lr0 + rr) * 40 + col] = fp8_enc(acc[rr]);
            } else {
#pragma unroll
                for (int rr = 0; rr < 4; ++rr)
                    sz2[lr0 + rr][col - N_CLS] = f2b(acc[rr]);
            }
        }
    }
    __syncthreads();
    int vrows = N_NODES - m0b; if (vrows > 64) vrows = 64;
    int nch = (vrows * 40) >> 4;        // 16 B chunks; vrows*40 divisible by 16
    for (int idx = tid; idx < nch; idx += 256)
        *(uint4*)(y2f8 + (size_t)m0b * 40 + idx * 16) = *(const uint4*)&sy2[idx * 16];
    for (int idx = tid; idx < vrows * 5; idx += 256) {
        int row = idx / 5, c = (idx - row * 5) * 8;   // ushorts; 8 = 16 B
        *(uint4*)(z2b + (size_t)(m0b + row) * HID + c) = *(const uint4*)&sz2[row][c];
    }
}

// ---------------------------------------------------------------------------
// agg2 + log_softmax. 4-lane group = one node (16 nodes/wave); y2 rows are
// 40 B packed. Lane 0/1 load 16-B quarter-rows, lane 2 loads 16 B of which
// 8 B valid (over-read lands in the next row, decoded into acc[8..15] which
// lane 2 never uses), lane 3 idle. One gather instruction fetches 16 rows
// per wave (was 4). Unroll-4 => 4 rows in flight per group.
// ---------------------------------------------------------------------------
__global__ void agg2_kernel(const int* __restrict__ rowptr,
                            const int* __restrict__ csr,
                            const uchar_t* __restrict__ y2f8,
                            const ushort_t* __restrict__ z2b,
                            const float* __restrict__ b2,
                            float* __restrict__ out) {
    int gid = blockIdx.x * blockDim.x + threadIdx.x;
    int wave = gid >> 6, lane = gid & 63;
    int g = lane >> 2, l = lane & 3;
    int n = wave * 16 + g;                // N_NODES % 16 == 0
    if (n >= N_NODES) return;
    int beg = rowptr[n], end = rowptr[n + 1];
    float acc[16];
#pragma unroll
    for (int j = 0; j < 16; ++j) acc[j] = 0.f;
    if (l < 3) {
        const uchar_t* yb = y2f8 + l * 16;
        int i = beg;
        for (; i + 3 < end; i += 4) {
            int s0 = csr[i], s1 = csr[i + 1], s2 = csr[i + 2], s3 = csr[i + 3];
            uint4 w0 = *(const uint4*)(yb + (size_t)s0 * 40);
            uint4 w1 = *(const uint4*)(yb + (size_t)s1 * 40);
            uint4 w2 = *(const uint4*)(yb + (size_t)s2 * 40);
            uint4 w3 = *(const uint4*)(yb + (size_t)s3 * 40);
            acc16(acc, w0); acc16(acc, w1); acc16(acc, w2); acc16(acc, w3);
        }
        for (; i < end; ++i) {
            uint4 w = *(const uint4*)(yb + (size_t)csr[i] * 40);
            acc16(acc, w);
        }
    }
    float inv = 1.0f / fmaxf((float)(end - beg), 1.0f);
    int c = l * 16;
    int nv = (l < 2) ? 16 : ((l == 2) ? 8 : 0);
    ushort_t zz[16];
    float bv[16];
#pragma unroll
    for (int j = 0; j < 16; ++j) { zz[j] = 0; bv[j] = 0.f; }
    if (l < 2) {
        *(uint4*)&zz[0] = *(const uint4*)(z2b + (size_t)n * HID + c);
        *(uint4*)&zz[8] = *(const uint4*)(z2b + (size_t)n * HID + c + 8);
        *(float4*)&bv[0]  = *(const float4*)(b2 + c);
        *(float4*)&bv[4]  = *(const float4*)(b2 + c + 4);
        *(float4*)&bv[8]  = *(const float4*)(b2 + c + 8);
        *(float4*)&bv[12] = *(const float4*)(b2 + c + 12);
    } else if (l == 2) {
        *(uint4*)&zz[0] = *(const uint4*)(z2b + (size_t)n * HID + c);
        *(float4*)&bv[0] = *(const float4*)(b2 + c);
        *(float4*)&bv[4] = *(const float4*)(b2 + c + 4);
    }
    float vv[16];
#pragma unroll
    for (int j = 0; j < 16; ++j)
        vv[j] = (j < nv) ? fmaf(acc[j], inv, bv[j] + b2f(zz[j])) : -INFINITY;

    float m = vv[0];
#pragma unroll
    for (int j = 1; j < 16; ++j) m = fmaxf(m, vv[j]);
    m = fmaxf(m, __shfl_xor(m, 1, 4));
    m = fmaxf(m, __shfl_xor(m, 2, 4));
    float s = 0.f;
#pragma unroll
    for (int j = 0; j < 16; ++j)
        if (vv[j] > -INFINITY) s += expf(vv[j] - m);
    s += __shfl_xor(s, 1, 4);
    s += __shfl_xor(s, 2, 4);
    float ls = logf(s);
    float* orow = out + (size_t)n * N_CLS + c;
    if (l < 2) {
        *(float4*)(orow)     = make_float4(vv[0] - m - ls, vv[1] - m - ls, vv[2] - m - ls, vv[3] - m - ls);
        *(float4*)(orow + 4) = make_float4(vv[4] - m - ls, vv[5] - m - ls, vv[6] - m - ls, vv[7] - m - ls);
        *(float4*)(orow + 8) = make_float4(vv[8] - m - ls, vv[9] - m - ls, vv[10] - m - ls, vv[11] - m - ls);
        *(float4*)(orow + 12) = make_float4(vv[12] - m - ls, vv[13] - m - ls, vv[14] - m - ls, vv[15] - m - ls);
    } else if (l == 2) {
        *(float4*)(orow)     = make_float4(vv[0] - m - ls, vv[1] - m - ls, vv[2] - m - ls, vv[3] - m - ls);
        *(float4*)(orow + 4) = make_float4(vv[4] - m - ls, vv[5] - m - ls, vv[6] - m - ls, vv[7] - m - ls);
    }
}

extern "C" void kernel_launch(void* const* d_in, const int* in_sizes, int n_in,
                              void* d_out, int out_size, void* d_ws, size_t ws_size,
                              hipStream_t stream) {
    const float* x   = (const float*)d_in[0];
    const int*   ei  = (const int*)d_in[1];
    const float* W1l = (const float*)d_in[2];
    const float* b1  = (const float*)d_in[3];
    const float* W1r = (const float*)d_in[4];
    const float* W2l = (const float*)d_in[5];
    const float* b2  = (const float*)d_in[6];
    const float* W2r = (const float*)d_in[7];
    float* out = (float*)d_out;
    const int E = in_sizes[1] / 2;
    const int nblk = (E + EPB - 1) / EPB;

    char* p = (char*)d_ws;
    auto take = [&](size_t bytes) {
        char* q = p;
        p += (bytes + 15) & ~(size_t)15;
        return (void*)q;
    };
    int* rowptr     = (int*)take(sizeof(int) * (N_NODES + 4));
    int* blockHist  = (int*)take(sizeof(int) * (size_t)nblk * NB);
    int* blockBase  = (int*)take(sizeof(int) * (size_t)nblk * NB);
    int* btot       = (int*)take(sizeof(int) * NB);
    uint_t* pairs   = (uint_t*)take(sizeof(uint_t) * (size_t)E);
    int* csr        = (int*)take(sizeof(int) * (size_t)E);
    ushort_t* W1t   = (ushort_t*)take(sizeof(ushort_t) * 128 * F_IN);
    ushort_t* W2t   = (ushort_t*)take(sizeof(ushort_t) * 80 * HID);
    uchar_t* y1f8   = (uchar_t*)take(sizeof(uchar_t) * (size_t)N_NODES * 64);
    ushort_t* z1b   = (ushort_t*)take(sizeof(ushort_t) * (size_t)N_NODES * HID);
    ushort_t* hb    = (ushort_t*)take(sizeof(ushort_t) * (size_t)N_NODES * HID);
    // y1f8 is 6.4 MB, dead after agg1: reuse for y2 (N*40 = 4.0 MB; agg2's
    // lane-2 16-B over-read stays inside the 6.4 MB region).
    uchar_t* y2f8 = y1f8;
    ushort_t* z2b = z1b;    // dead after agg1; stride-64 rows, 40 real cols

    const int B = 256;

    block_hist_kernel<<<nblk, 256, 0, stream>>>(ei, E, blockHist);
    col_scan_kernel<<<NB, 256, 0, stream>>>(blockHist, nblk, blockBase, btot);
    scatter_pairs_kernel<<<nblk, 256, 0, stream>>>(ei, E, blockBase, btot, pairs);
    bucket_sort_kernel<<<NB, BSZ, 0, stream>>>(pairs, btot, rowptr, csr);

    cvt_w_kernel<<<(128 * F_IN + 80 * HID + B - 1) / B, B, 0, stream>>>(
        W1l, W1r, W2l, W2r, W1t, W2t);

    int gemm_blocks = (MT + 3) / 4;     // 4 tiles (64 rows) per block
    int t_agg = (N_NODES / 16) * 64;    // 16 nodes per wave (4-lane groups)

    gemm1_mfma_kernel<<<gemm_blocks, B, 0, stream>>>(x, W1t, y1f8, z1b);
    agg1_kernel<<<(t_agg + B - 1) / B, B, 0, stream>>>(rowptr, csr, y1f8, z1b, b1, hb);
    gemm2_mfma_kernel<<<gemm_blocks, B, 0, stream>>>(hb, W2t, y2f8, z2b);
    agg2_kernel<<<(t_agg + B - 1) / B, B, 0, stream>>>(rowptr, csr, y2f8, z2b, b2, out);
}

// Round 8
// 232.785 us; speedup vs baseline: 1.7222x; 1.0585x over previous
//
#include <hip/hip_runtime.h>
#include <math.h>

#define N_NODES 100000
#define F_IN    128
#define HID     64
#define N_CLS   40
#define MT      (N_NODES / 16)                  // 6250 M-tiles of 16 nodes

#define BSHIFT  9
#define BSZ     512                              // dsts per coarse bucket
#define NB      ((N_NODES + BSZ - 1) / BSZ)      // 196 buckets
#define EPB     4096                             // edges per block in sort passes

typedef __attribute__((ext_vector_type(8))) short bf8_t;   // 8 bf16 (4 VGPR)
typedef __attribute__((ext_vector_type(4))) float f4_t;    // MFMA C/D frag
typedef __attribute__((ext_vector_type(2))) float f2v_t;

typedef unsigned short ushort_t;
typedef unsigned int uint_t;
typedef unsigned char uchar_t;

__device__ __forceinline__ ushort_t f2b(float f) {   // f32 -> bf16 RNE
    union { float f; uint_t u; } c; c.f = f;
    uint_t u = c.u + 0x7FFFu + ((c.u >> 16) & 1u);
    return (ushort_t)(u >> 16);
}
__device__ __forceinline__ float b2f(ushort_t h) {
    union { uint_t u; float f; } c; c.u = ((uint_t)h) << 16;
    return c.f;
}

// ---- fp8 e4m3 (OCP) helpers: HW cvt if available, manual fallback ---------
#if defined(__has_builtin)
#if __has_builtin(__builtin_amdgcn_cvt_pk_f32_fp8) && __has_builtin(__builtin_amdgcn_cvt_pk_fp8_f32)
#define HAVE_FP8_HW 1
#endif
#endif

__device__ __forceinline__ uchar_t fp8_enc(float v) {
#ifdef HAVE_FP8_HW
    return (uchar_t)(__builtin_amdgcn_cvt_pk_fp8_f32(v, v, 0, false) & 0xff);
#else
    union { float f; uint_t u; } c; c.f = v;
    uint_t s = c.u >> 31;
    float av = fabsf(v);
    if (av > 448.f) av = 448.f;
    int e;
    float m = frexpf(av, &e);          // av = m * 2^e, m in [0.5,1)
    int ee = e + 6;                    // biased for e4m3 (bias 7, m in [1,2))
    uchar_t r;
    if (av == 0.f) r = 0;
    else if (ee <= 0) {                // denormal
        int q = (int)(av * 512.f + 0.5f);   // units of 2^-9
        if (q > 7) q = 7;
        r = (uchar_t)q;
    } else {
        int q = (int)(m * 16.f + 0.5f);     // m*16 in [8,16]
        if (q == 16) { q = 8; ee += 1; }
        if (ee > 15) { ee = 15; q = 15; }   // clamp toward max finite
        r = (uchar_t)((ee << 3) | (q & 7));
    }
    return r | (uchar_t)(s << 7);
#endif
}

__device__ __forceinline__ f2v_t fp8x2_dec_lo(uint_t w) {
#ifdef HAVE_FP8_HW
    return __builtin_amdgcn_cvt_pk_f32_fp8(w, false);
#else
    f2v_t r;
    for (int k = 0; k < 2; ++k) {
        uchar_t b = (w >> (8 * k)) & 0xff;
        uint_t s = (b >> 7) & 1, e = (b >> 3) & 15, m = b & 7;
        float f;
        if (e) { union { uint_t u; float ff; } c;
                 c.u = (s << 31) | ((e + 120) << 23) | (m << 20); f = c.ff; }
        else   { f = (float)m * 0.001953125f; if (s) f = -f; }
        r[k] = f;
    }
    return r;
#endif
}
__device__ __forceinline__ f2v_t fp8x2_dec_hi(uint_t w) {
#ifdef HAVE_FP8_HW
    return __builtin_amdgcn_cvt_pk_f32_fp8(w, true);
#else
    return fp8x2_dec_lo(w >> 16);
#endif
}

// ---------------------------------------------------------------------------
// Sort pass 1: per-block LDS histogram over 196 coarse buckets (dst >> 9).
// ---------------------------------------------------------------------------
__global__ void block_hist_kernel(const int* __restrict__ ei, int E,
                                  int* __restrict__ blockHist) {
    __shared__ int cnt[NB];
    int t = threadIdx.x, blk = blockIdx.x;
    for (int i = t; i < NB; i += 256) cnt[i] = 0;
    __syncthreads();
    int e0 = blk * EPB;
#pragma unroll
    for (int i = 0; i < EPB / 256; ++i) {
        int e = e0 + i * 256 + t;
        if (e < E) atomicAdd(&cnt[ei[E + e] >> BSHIFT], 1);
    }
    __syncthreads();
    for (int i = t; i < NB; i += 256) blockHist[blk * NB + i] = cnt[i];
}

// ---------------------------------------------------------------------------
// Sort pass 2: per-bin exclusive scan down the blocks.
// ---------------------------------------------------------------------------
__global__ void col_scan_kernel(const int* __restrict__ blockHist, int nblk,
                                int* __restrict__ blockBase,
                                int* __restrict__ btot) {
    __shared__ int ss[256];
    __shared__ int carry;
    int bin = blockIdx.x, t = threadIdx.x;
    if (t == 0) carry = 0;
    __syncthreads();
    for (int c0 = 0; c0 < nblk; c0 += 256) {
        int b = c0 + t;
        int v = (b < nblk) ? blockHist[b * NB + bin] : 0;
        ss[t] = v;
        __syncthreads();
        for (int off = 1; off < 256; off <<= 1) {
            int u = (t >= off) ? ss[t - off] : 0;
            __syncthreads();
            ss[t] += u;
            __syncthreads();
        }
        if (b < nblk) blockBase[b * NB + bin] = carry + ss[t] - v;
        __syncthreads();
        if (t == 255) carry += ss[255];
        __syncthreads();
    }
    if (t == 0) btot[bin] = carry;
}

// ---------------------------------------------------------------------------
// Sort pass 3: scatter packed (src<<9 | dst&511) into coarse-bucket order.
// Bucket base offsets computed locally from btot (196-elem LDS scan).
// ---------------------------------------------------------------------------
__global__ void scatter_pairs_kernel(const int* __restrict__ ei, int E,
                                     const int* __restrict__ blockBase,
                                     const int* __restrict__ btot,
                                     uint_t* __restrict__ pairs) {
    __shared__ int cur[NB];
    __shared__ int base[NB];
    __shared__ int ss[256];
    int t = threadIdx.x, blk = blockIdx.x;
    int v = (t < NB) ? btot[t] : 0;
    ss[t] = v;
    __syncthreads();
    for (int off = 1; off < 256; off <<= 1) {
        int u = (t >= off) ? ss[t - off] : 0;
        __syncthreads();
        ss[t] += u;
        __syncthreads();
    }
    if (t < NB) {
        cur[t] = 0;
        base[t] = (ss[t] - v) + blockBase[blk * NB + t];
    }
    __syncthreads();
    int e0 = blk * EPB;
#pragma unroll
    for (int i = 0; i < EPB / 256; ++i) {
        int e = e0 + i * 256 + t;
        if (e < E) {
            int src = ei[e];
            int dst = ei[E + e];
            int bin = dst >> BSHIFT;
            int r = atomicAdd(&cur[bin], 1);   // LDS atomic
            pairs[base[bin] + r] = ((uint_t)src << BSHIFT) | (uint_t)(dst & (BSZ - 1));
        }
    }
}

// ---------------------------------------------------------------------------
// Sort pass 4: per-bucket fine sort. Bucket base computed locally
// from btot; rowptr + contiguous csr region; rowptr[N] written by last bin.
// ---------------------------------------------------------------------------
__global__ void bucket_sort_kernel(const uint_t* __restrict__ pairs,
                                   const int* __restrict__ btot,
                                   int* __restrict__ rowptr,
                                   int* __restrict__ csr) {
    __shared__ int hist[BSZ];
    __shared__ int lofs[BSZ];
    int bin = blockIdx.x, t = threadIdx.x;
    // local exclusive prefix of btot over 196 bins (inclusive scan, then shift)
    int pv = (t < NB) ? btot[t] : 0;
    lofs[t] = pv;
    __syncthreads();
    for (int off = 1; off < BSZ; off <<= 1) {
        int u = (t >= off) ? lofs[t - off] : 0;
        __syncthreads();
        lofs[t] += u;
        __syncthreads();
    }
    int base = (bin > 0) ? lofs[bin - 1] : 0;   // broadcast LDS read
    int cnt = btot[bin];
    __syncthreads();
    hist[t] = 0;
    __syncthreads();
    for (int i = t; i < cnt; i += BSZ)
        atomicAdd(&hist[pairs[base + i] & (BSZ - 1)], 1);
    __syncthreads();
    int v = hist[t];
    lofs[t] = v;
    __syncthreads();
    for (int off = 1; off < BSZ; off <<= 1) {
        int u = (t >= off) ? lofs[t - off] : 0;
        __syncthreads();
        lofs[t] += u;
        __syncthreads();
    }
    int excl = lofs[t] - v;
    int d_global = (bin << BSHIFT) + t;
    if (d_global < N_NODES) rowptr[d_global] = base + excl;
    if (bin == NB - 1 && t == 0) rowptr[N_NODES] = base + cnt;
    __syncthreads();
    lofs[t] = excl;
    hist[t] = 0;
    __syncthreads();
    for (int i = t; i < cnt; i += BSZ) {
        uint_t p = pairs[base + i];
        int lb = p & (BSZ - 1);
        int r = atomicAdd(&hist[lb], 1);
        csr[base + lofs[lb] + r] = (int)(p >> BSHIFT);
    }
}

// ---------------------------------------------------------------------------
// cvt_w: bf16 [n][k]-major weight tensors.
// ---------------------------------------------------------------------------
__global__ void cvt_w_kernel(const float* __restrict__ W1l,
                             const float* __restrict__ W1r,
                             const float* __restrict__ W2l,
                             const float* __restrict__ W2r,
                             ushort_t* __restrict__ W1t,
                             ushort_t* __restrict__ W2t) {
    int t = blockIdx.x * blockDim.x + threadIdx.x;
    if (t < 128 * F_IN) {
        int n = t / F_IN, k = t - n * F_IN;
        float v = (n < HID) ? W1l[k * HID + n] : W1r[k * HID + (n - HID)];
        W1t[t] = f2b(v);
    } else if (t < 128 * F_IN + 80 * HID) {
        int u = t - 128 * F_IN;
        int n = u / HID, k = u - n * HID;
        float v = (n < N_CLS) ? W2l[k * N_CLS + n] : W2r[k * N_CLS + (n - N_CLS)];
        W2t[u] = f2b(v);
    }
}

// ---------------------------------------------------------------------------
// gemm1_mfma: y1(fp8, 64 B rows) | z1(bf16) = x @ [W1_l|W1_r].
// 2 tiles (32 rows) per wave: each W1t B-fragment feeds 8 MFMAs (was 4),
// W1t load instructions halved, x-phase issues 16 outstanding loads.
// Block = 4 waves = 128 rows. LDS-staged outputs, contiguous wide stores.
// ---------------------------------------------------------------------------
__global__ void gemm1_mfma_kernel(const float* __restrict__ x,
                                  const ushort_t* __restrict__ W1t,
                                  uchar_t* __restrict__ y1f8,
                                  ushort_t* __restrict__ z1b) {
    __shared__ uchar_t sy[128][80];    // 10240 B, rows padded 64->80
    __shared__ ushort_t sz[128][72];   // 18432 B, rows padded 64->72
    int tid = threadIdx.x;
    int wave = tid >> 6, lane = tid & 63;
    int tile0 = blockIdx.x * 8 + wave * 2;     // 2 consecutive tiles per wave
    int m0b = blockIdx.x * 128;
    int r = lane & 15, q = lane >> 4;
    bool v0 = (tile0 < MT), v1 = (tile0 + 1 < MT);

    bf8_t a0[4], a1[4];
#pragma unroll
    for (int kt = 0; kt < 4; ++kt) { a0[kt] = (bf8_t)(short)0; a1[kt] = (bf8_t)(short)0; }
    if (v0) {
        const float* xr = x + (size_t)(tile0 * 16 + r) * F_IN + q * 8;
#pragma unroll
        for (int kt = 0; kt < 4; ++kt) {
            float4 u = *(const float4*)(xr + kt * 32);
            float4 v = *(const float4*)(xr + kt * 32 + 4);
            bf8_t tt;
            tt[0] = (short)f2b(u.x); tt[1] = (short)f2b(u.y);
            tt[2] = (short)f2b(u.z); tt[3] = (short)f2b(u.w);
            tt[4] = (short)f2b(v.x); tt[5] = (short)f2b(v.y);
            tt[6] = (short)f2b(v.z); tt[7] = (short)f2b(v.w);
            a0[kt] = tt;
        }
    }
    if (v1) {
        const float* xr = x + (size_t)((tile0 + 1) * 16 + r) * F_IN + q * 8;
#pragma unroll
        for (int kt = 0; kt < 4; ++kt) {
            float4 u = *(const float4*)(xr + kt * 32);
            float4 v = *(const float4*)(xr + kt * 32 + 4);
            bf8_t tt;
            tt[0] = (short)f2b(u.x); tt[1] = (short)f2b(u.y);
            tt[2] = (short)f2b(u.z); tt[3] = (short)f2b(u.w);
            tt[4] = (short)f2b(v.x); tt[5] = (short)f2b(v.y);
            tt[6] = (short)f2b(v.z); tt[7] = (short)f2b(v.w);
            a1[kt] = tt;
        }
    }
    int lr0 = wave * 32 + q * 4;       // row base within block for tile 0
#pragma unroll
    for (int tn = 0; tn < 8; ++tn) {
        const ushort_t* wr = W1t + (size_t)(tn * 16 + r) * F_IN + q * 8;
        bf8_t b[4];
#pragma unroll
        for (int kt = 0; kt < 4; ++kt)
            b[kt] = *(const bf8_t*)(wr + kt * 32);
        f4_t acc0 = {0.f, 0.f, 0.f, 0.f};
        f4_t acc1 = {0.f, 0.f, 0.f, 0.f};
#pragma unroll
        for (int kt = 0; kt < 4; ++kt) {
            acc0 = __builtin_amdgcn_mfma_f32_16x16x32_bf16(a0[kt], b[kt], acc0, 0, 0, 0);
            acc1 = __builtin_amdgcn_mfma_f32_16x16x32_bf16(a1[kt], b[kt], acc1, 0, 0, 0);
        }
        int col = tn * 16 + r;
        if (col < 64) {
            if (v0) {
#pragma unroll
                for (int rr = 0; rr < 4; ++rr) sy[lr0 + rr][col] = fp8_enc(acc0[rr]);
            }
            if (v1) {
#pragma unroll
                for (int rr = 0; rr < 4; ++rr) sy[lr0 + 16 + rr][col] = fp8_enc(acc1[rr]);
            }
        } else {
            if (v0) {
#pragma unroll
                for (int rr = 0; rr < 4; ++rr) sz[lr0 + rr][col - 64] = f2b(acc0[rr]);
            }
            if (v1) {
#pragma unroll
                for (int rr = 0; rr < 4; ++rr) sz[lr0 + 16 + rr][col - 64] = f2b(acc1[rr]);
            }
        }
    }
    __syncthreads();
    int vrows = N_NODES - m0b; if (vrows > 128) vrows = 128;
    for (int idx = tid; idx < vrows * 4; idx += 256) {
        int row = idx >> 2, c = (idx & 3) << 4;
        *(uint4*)(y1f8 + (size_t)(m0b + row) * 64 + c) = *(const uint4*)&sy[row][c];
    }
    for (int idx = tid; idx < vrows * 8; idx += 256) {
        int row = idx >> 3, c = (idx & 7) << 3;      // ushort offset, 8 = 16 B
        *(uint4*)(z1b + (size_t)(m0b + row) * HID + c) = *(const uint4*)&sz[row][c];
    }
}

// ---------------------------------------------------------------------------
// agg1: h = relu(mean y1[src] + b1 + z1).
// 4-lane group = one node (16 nodes/wave); lane l owns cols l*16..l*16+15 and
// fetches its 16-B quarter-row with ONE dwordx4. Unroll-4 => 4 independent
// row-gathers in flight per group (64 outstanding 16-B loads per wave).
// ---------------------------------------------------------------------------
__device__ __forceinline__ void acc16(float* acc, uint4 v) {
    f2v_t p;
    p = fp8x2_dec_lo(v.x); acc[0]  += p[0]; acc[1]  += p[1];
    p = fp8x2_dec_hi(v.x); acc[2]  += p[0]; acc[3]  += p[1];
    p = fp8x2_dec_lo(v.y); acc[4]  += p[0]; acc[5]  += p[1];
    p = fp8x2_dec_hi(v.y); acc[6]  += p[0]; acc[7]  += p[1];
    p = fp8x2_dec_lo(v.z); acc[8]  += p[0]; acc[9]  += p[1];
    p = fp8x2_dec_hi(v.z); acc[10] += p[0]; acc[11] += p[1];
    p = fp8x2_dec_lo(v.w); acc[12] += p[0]; acc[13] += p[1];
    p = fp8x2_dec_hi(v.w); acc[14] += p[0]; acc[15] += p[1];
}

__global__ void agg1_kernel(const int* __restrict__ rowptr,
                            const int* __restrict__ csr,
                            const uchar_t* __restrict__ y1f8,
                            const ushort_t* __restrict__ z1b,
                            const float* __restrict__ b1,
                            ushort_t* __restrict__ hb) {
    int gid = blockIdx.x * blockDim.x + threadIdx.x;
    int wave = gid >> 6, lane = gid & 63;
    int g = lane >> 2, l = lane & 3;
    int n = wave * 16 + g;                // N_NODES % 16 == 0
    if (n >= N_NODES) return;
    int beg = rowptr[n], end = rowptr[n + 1];
    float acc[16];
#pragma unroll
    for (int j = 0; j < 16; ++j) acc[j] = 0.f;
    const uchar_t* yb = y1f8 + l * 16;
    int i = beg;
    for (; i + 3 < end; i += 4) {
        int s0 = csr[i], s1 = csr[i + 1], s2 = csr[i + 2], s3 = csr[i + 3];
        uint4 w0 = *(const uint4*)(yb + (size_t)s0 * 64);
        uint4 w1 = *(const uint4*)(yb + (size_t)s1 * 64);
        uint4 w2 = *(const uint4*)(yb + (size_t)s2 * 64);
        uint4 w3 = *(const uint4*)(yb + (size_t)s3 * 64);
        acc16(acc, w0); acc16(acc, w1); acc16(acc, w2); acc16(acc, w3);
    }
    for (; i < end; ++i) {
        uint4 w = *(const uint4*)(yb + (size_t)csr[i] * 64);
        acc16(acc, w);
    }
    float inv = 1.0f / fmaxf((float)(end - beg), 1.0f);
    int c = l * 16;
    ushort_t zz[16];
    *(uint4*)&zz[0] = *(const uint4*)(z1b + (size_t)n * HID + c);
    *(uint4*)&zz[8] = *(const uint4*)(z1b + (size_t)n * HID + c + 8);
    float bv[16];
    *(float4*)&bv[0]  = *(const float4*)(b1 + c);
    *(float4*)&bv[4]  = *(const float4*)(b1 + c + 4);
    *(float4*)&bv[8]  = *(const float4*)(b1 + c + 8);
    *(float4*)&bv[12] = *(const float4*)(b1 + c + 12);
    ushort_t o[16];
#pragma unroll
    for (int j = 0; j < 16; ++j) {
        float r = fmaxf(fmaf(acc[j], inv, bv[j] + b2f(zz[j])), 0.f);
        o[j] = f2b(r);
    }
    *(uint4*)(hb + (size_t)n * HID + c)     = *(const uint4*)&o[0];
    *(uint4*)(hb + (size_t)n * HID + c + 8) = *(const uint4*)&o[8];
}

// ---------------------------------------------------------------------------
// gemm2_mfma: y2(fp8, 40 B packed rows) | z2(bf16, stride 64) = h @ [W2l|W2r].
// LDS-staged outputs, contiguous wide stores (y2 block region = 2560 B flat).
// ---------------------------------------------------------------------------
__global__ void gemm2_mfma_kernel(const ushort_t* __restrict__ hb,
                                  const ushort_t* __restrict__ W2t,
                                  uchar_t* __restrict__ y2f8,
                                  ushort_t* __restrict__ z2b) {
    __shared__ uchar_t sy2[64 * 40];    // 2560 B flat (block y2 region image)
    __shared__ ushort_t sz2[64][56];    // 7168 B, rows padded 40->56
    int tid = threadIdx.x;
    int wave = tid >> 6, lane = tid & 63;
    int tile = blockIdx.x * 4 + wave;
    int m0b = blockIdx.x * 64;
    if (tile < MT) {
        int m0 = tile * 16;
        int r = lane & 15, q = lane >> 4;
        const ushort_t* hr = hb + (size_t)(m0 + r) * HID + q * 8;
        bf8_t a[2];
#pragma unroll
        for (int kt = 0; kt < 2; ++kt)
            a[kt] = *(const bf8_t*)(hr + kt * 32);
        int lr0 = wave * 16 + q * 4;
#pragma unroll
        for (int tn = 0; tn < 5; ++tn) {
            const ushort_t* wr = W2t + (size_t)(tn * 16 + r) * HID + q * 8;
            f4_t acc = {0.f, 0.f, 0.f, 0.f};
#pragma unroll
            for (int kt = 0; kt < 2; ++kt) {
                bf8_t b = *(const bf8_t*)(wr + kt * 32);
                acc = __builtin_amdgcn_mfma_f32_16x16x32_bf16(a[kt], b, acc, 0, 0, 0);
            }
            int col = tn * 16 + r;
            if (col < N_CLS) {
#pragma unroll
                for (int rr = 0; rr < 4; ++rr)
                    sy2[(lr0 + rr) * 40 + col] = fp8_enc(acc[rr]);
            } else {
#pragma unroll
                for (int rr = 0; rr < 4; ++rr)
                    sz2[lr0 + rr][col - N_CLS] = f2b(acc[rr]);
            }
        }
    }
    __syncthreads();
    int vrows = N_NODES - m0b; if (vrows > 64) vrows = 64;
    int nch = (vrows * 40) >> 4;        // 16 B chunks; vrows*40 divisible by 16
    for (int idx = tid; idx < nch; idx += 256)
        *(uint4*)(y2f8 + (size_t)m0b * 40 + idx * 16) = *(const uint4*)&sy2[idx * 16];
    for (int idx = tid; idx < vrows * 5; idx += 256) {
        int row = idx / 5, c = (idx - row * 5) * 8;   // ushorts; 8 = 16 B
        *(uint4*)(z2b + (size_t)(m0b + row) * HID + c) = *(const uint4*)&sz2[row][c];
    }
}

// ---------------------------------------------------------------------------
// agg2 + log_softmax (round-4 version: best measured). One 16-lane group =
// one node; y2 rows are 40 B packed. Gather predicated under l<10
// (exec-masked lanes issue no VMEM traffic). Unroll-8 batched index loads.
// ---------------------------------------------------------------------------
__global__ void agg2_kernel(const int* __restrict__ rowptr,
                            const int* __restrict__ csr,
                            const uchar_t* __restrict__ y2f8,
                            const ushort_t* __restrict__ z2b,
                            const float* __restrict__ b2,
                            float* __restrict__ out) {
    int gid = blockIdx.x * blockDim.x + threadIdx.x;
    int wave = gid >> 6, lane = gid & 63;
    int g = lane >> 4, l = lane & 15;
    int n = wave * 4 + g;
    if (n >= N_NODES) return;
    int beg = rowptr[n], end = rowptr[n + 1];
    float a0 = 0.f, a1 = 0.f, a2 = 0.f, a3 = 0.f;
    float4 bb = make_float4(0.f, 0.f, 0.f, 0.f);
    ushort4 zz; zz.x = 0; zz.y = 0; zz.z = 0; zz.w = 0;
    int c0 = l * 4;
    if (l < 10) {
        int i = beg;
        for (; i + 7 < end; i += 8) {
            int s0 = csr[i],     s1 = csr[i + 1], s2 = csr[i + 2], s3 = csr[i + 3];
            int s4 = csr[i + 4], s5 = csr[i + 5], s6 = csr[i + 6], s7 = csr[i + 7];
            uint_t w0 = *(const uint_t*)(y2f8 + (size_t)s0 * 40 + c0);
            uint_t w1 = *(const uint_t*)(y2f8 + (size_t)s1 * 40 + c0);
            uint_t w2 = *(const uint_t*)(y2f8 + (size_t)s2 * 40 + c0);
            uint_t w3 = *(const uint_t*)(y2f8 + (size_t)s3 * 40 + c0);
            uint_t w4 = *(const uint_t*)(y2f8 + (size_t)s4 * 40 + c0);
            uint_t w5 = *(const uint_t*)(y2f8 + (size_t)s5 * 40 + c0);
            uint_t w6 = *(const uint_t*)(y2f8 + (size_t)s6 * 40 + c0);
            uint_t w7 = *(const uint_t*)(y2f8 + (size_t)s7 * 40 + c0);
            f2v_t p;
            p = fp8x2_dec_lo(w0); a0 += p[0]; a1 += p[1];
            p = fp8x2_dec_hi(w0); a2 += p[0]; a3 += p[1];
            p = fp8x2_dec_lo(w1); a0 += p[0]; a1 += p[1];
            p = fp8x2_dec_hi(w1); a2 += p[0]; a3 += p[1];
            p = fp8x2_dec_lo(w2); a0 += p[0]; a1 += p[1];
            p = fp8x2_dec_hi(w2); a2 += p[0]; a3 += p[1];
            p = fp8x2_dec_lo(w3); a0 += p[0]; a1 += p[1];
            p = fp8x2_dec_hi(w3); a2 += p[0]; a3 += p[1];
            p = fp8x2_dec_lo(w4); a0 += p[0]; a1 += p[1];
            p = fp8x2_dec_hi(w4); a2 += p[0]; a3 += p[1];
            p = fp8x2_dec_lo(w5); a0 += p[0]; a1 += p[1];
            p = fp8x2_dec_hi(w5); a2 += p[0]; a3 += p[1];
            p = fp8x2_dec_lo(w6); a0 += p[0]; a1 += p[1];
            p = fp8x2_dec_hi(w6); a2 += p[0]; a3 += p[1];
            p = fp8x2_dec_lo(w7); a0 += p[0]; a1 += p[1];
            p = fp8x2_dec_hi(w7); a2 += p[0]; a3 += p[1];
        }
        for (; i + 3 < end; i += 4) {
            int s0 = csr[i], s1 = csr[i + 1], s2 = csr[i + 2], s3 = csr[i + 3];
            uint_t w0 = *(const uint_t*)(y2f8 + (size_t)s0 * 40 + c0);
            uint_t w1 = *(const uint_t*)(y2f8 + (size_t)s1 * 40 + c0);
            uint_t w2 = *(const uint_t*)(y2f8 + (size_t)s2 * 40 + c0);
            uint_t w3 = *(const uint_t*)(y2f8 + (size_t)s3 * 40 + c0);
            f2v_t p;
            p = fp8x2_dec_lo(w0); a0 += p[0]; a1 += p[1];
            p = fp8x2_dec_hi(w0); a2 += p[0]; a3 += p[1];
            p = fp8x2_dec_lo(w1); a0 += p[0]; a1 += p[1];
            p = fp8x2_dec_hi(w1); a2 += p[0]; a3 += p[1];
            p = fp8x2_dec_lo(w2); a0 += p[0]; a1 += p[1];
            p = fp8x2_dec_hi(w2); a2 += p[0]; a3 += p[1];
            p = fp8x2_dec_lo(w3); a0 += p[0]; a1 += p[1];
            p = fp8x2_dec_hi(w3); a2 += p[0]; a3 += p[1];
        }
        for (; i < end; ++i) {
            uint_t w = *(const uint_t*)(y2f8 + (size_t)csr[i] * 40 + c0);
            f2v_t p0 = fp8x2_dec_lo(w), p1 = fp8x2_dec_hi(w);
            a0 += p0[0]; a1 += p0[1]; a2 += p1[0]; a3 += p1[1];
        }
        bb = *(const float4*)(b2 + c0);
        zz = *(const ushort4*)(z2b + (size_t)n * HID + c0);
    }
    float inv = 1.0f / fmaxf((float)(end - beg), 1.0f);
    float v0 = (c0 + 0 < N_CLS) ? fmaf(a0, inv, bb.x + b2f(zz.x)) : -INFINITY;
    float v1 = (c0 + 1 < N_CLS) ? fmaf(a1, inv, bb.y + b2f(zz.y)) : -INFINITY;
    float v2 = (c0 + 2 < N_CLS) ? fmaf(a2, inv, bb.z + b2f(zz.z)) : -INFINITY;
    float v3 = (c0 + 3 < N_CLS) ? fmaf(a3, inv, bb.w + b2f(zz.w)) : -INFINITY;

    float m = fmaxf(fmaxf(v0, v1), fmaxf(v2, v3));
#pragma unroll
    for (int off = 1; off < 16; off <<= 1)
        m = fmaxf(m, __shfl_xor(m, off, 64));
    float s = 0.f;
    if (v0 > -INFINITY) s += expf(v0 - m);
    if (v1 > -INFINITY) s += expf(v1 - m);
    if (v2 > -INFINITY) s += expf(v2 - m);
    if (v3 > -INFINITY) s += expf(v3 - m);
#pragma unroll
    for (int off = 1; off < 16; off <<= 1)
        s += __shfl_xor(s, off, 64);
    float ls = logf(s);
    if (l < 10) {
        float4 o = make_float4(v0 - m - ls, v1 - m - ls, v2 - m - ls, v3 - m - ls);
        *(float4*)(out + (size_t)n * N_CLS + c0) = o;
    }
}

extern "C" void kernel_launch(void* const* d_in, const int* in_sizes, int n_in,
                              void* d_out, int out_size, void* d_ws, size_t ws_size,
                              hipStream_t stream) {
    const float* x   = (const float*)d_in[0];
    const int*   ei  = (const int*)d_in[1];
    const float* W1l = (const float*)d_in[2];
    const float* b1  = (const float*)d_in[3];
    const float* W1r = (const float*)d_in[4];
    const float* W2l = (const float*)d_in[5];
    const float* b2  = (const float*)d_in[6];
    const float* W2r = (const float*)d_in[7];
    float* out = (float*)d_out;
    const int E = in_sizes[1] / 2;
    const int nblk = (E + EPB - 1) / EPB;

    char* p = (char*)d_ws;
    auto take = [&](size_t bytes) {
        char* q = p;
        p += (bytes + 15) & ~(size_t)15;
        return (void*)q;
    };
    int* rowptr     = (int*)take(sizeof(int) * (N_NODES + 4));
    int* blockHist  = (int*)take(sizeof(int) * (size_t)nblk * NB);
    int* blockBase  = (int*)take(sizeof(int) * (size_t)nblk * NB);
    int* btot       = (int*)take(sizeof(int) * NB);
    uint_t* pairs   = (uint_t*)take(sizeof(uint_t) * (size_t)E);
    int* csr        = (int*)take(sizeof(int) * (size_t)E);
    ushort_t* W1t   = (ushort_t*)take(sizeof(ushort_t) * 128 * F_IN);
    ushort_t* W2t   = (ushort_t*)take(sizeof(ushort_t) * 80 * HID);
    uchar_t* y1f8   = (uchar_t*)take(sizeof(uchar_t) * (size_t)N_NODES * 64);
    ushort_t* z1b   = (ushort_t*)take(sizeof(ushort_t) * (size_t)N_NODES * HID);
    ushort_t* hb    = (ushort_t*)take(sizeof(ushort_t) * (size_t)N_NODES * HID);
    // y1f8 is 6.4 MB, dead after agg1: reuse for y2 (N*40 = 4.0 MB).
    uchar_t* y2f8 = y1f8;
    ushort_t* z2b = z1b;    // dead after agg1; stride-64 rows, 40 real cols

    const int B = 256;

    block_hist_kernel<<<nblk, 256, 0, stream>>>(ei, E, blockHist);
    col_scan_kernel<<<NB, 256, 0, stream>>>(blockHist, nblk, blockBase, btot);
    scatter_pairs_kernel<<<nblk, 256, 0, stream>>>(ei, E, blockBase, btot, pairs);
    bucket_sort_kernel<<<NB, BSZ, 0, stream>>>(pairs, btot, rowptr, csr);

    cvt_w_kernel<<<(128 * F_IN + 80 * HID + B - 1) / B, B, 0, stream>>>(
        W1l, W1r, W2l, W2r, W1t, W2t);

    int gemm1_blocks = (MT + 7) / 8;    // 8 tiles (128 rows) per block
    int gemm2_blocks = (MT + 3) / 4;    // 4 tiles (64 rows) per block
    int t_agg1 = (N_NODES / 16) * 64;   // 16 nodes per wave (4-lane groups)
    int t_agg2 = (N_NODES / 4) * 64;    // 4 nodes per wave (16-lane groups)

    gemm1_mfma_kernel<<<gemm1_blocks, B, 0, stream>>>(x, W1t, y1f8, z1b);
    agg1_kernel<<<(t_agg1 + B - 1) / B, B, 0, stream>>>(rowptr, csr, y1f8, z1b, b1, hb);
    gemm2_mfma_kernel<<<gemm2_blocks, B, 0, stream>>>(hb, W2t, y2f8, z2b);
    agg2_kernel<<<(t_agg2 + B - 1) / B, B, 0, stream>>>(rowptr, csr, y2f8, z2b, b2, out);
}

// Round 9
// 232.066 us; speedup vs baseline: 1.7275x; 1.0031x over previous
//
#include <hip/hip_runtime.h>
#include <math.h>

#define N_NODES 100000
#define F_IN    128
#define HID     64
#define N_CLS   40
#define MT      (N_NODES / 16)                  // 6250 M-tiles of 16 nodes

#define BSHIFT  9
#define BSZ     512                              // dsts per coarse bucket
#define NB      ((N_NODES + BSZ - 1) / BSZ)      // 196 buckets
#define EPB     4096                             // edges per block in sort passes

typedef __attribute__((ext_vector_type(8))) short bf8_t;   // 8 bf16 (4 VGPR)
typedef __attribute__((ext_vector_type(4))) float f4_t;    // MFMA C/D frag
typedef __attribute__((ext_vector_type(2))) float f2v_t;

typedef unsigned short ushort_t;
typedef unsigned int uint_t;
typedef unsigned char uchar_t;

__device__ __forceinline__ ushort_t f2b(float f) {   // f32 -> bf16 RNE
    union { float f; uint_t u; } c; c.f = f;
    uint_t u = c.u + 0x7FFFu + ((c.u >> 16) & 1u);
    return (ushort_t)(u >> 16);
}
__device__ __forceinline__ float b2f(ushort_t h) {
    union { uint_t u; float f; } c; c.u = ((uint_t)h) << 16;
    return c.f;
}

// ---- fp8 e4m3 (OCP) helpers: HW cvt if available, manual fallback ---------
#if defined(__has_builtin)
#if __has_builtin(__builtin_amdgcn_cvt_pk_f32_fp8) && __has_builtin(__builtin_amdgcn_cvt_pk_fp8_f32)
#define HAVE_FP8_HW 1
#endif
#endif

__device__ __forceinline__ uchar_t fp8_enc(float v) {
#ifdef HAVE_FP8_HW
    return (uchar_t)(__builtin_amdgcn_cvt_pk_fp8_f32(v, v, 0, false) & 0xff);
#else
    union { float f; uint_t u; } c; c.f = v;
    uint_t s = c.u >> 31;
    float av = fabsf(v);
    if (av > 448.f) av = 448.f;
    int e;
    float m = frexpf(av, &e);          // av = m * 2^e, m in [0.5,1)
    int ee = e + 6;                    // biased for e4m3 (bias 7, m in [1,2))
    uchar_t r;
    if (av == 0.f) r = 0;
    else if (ee <= 0) {                // denormal
        int q = (int)(av * 512.f + 0.5f);   // units of 2^-9
        if (q > 7) q = 7;
        r = (uchar_t)q;
    } else {
        int q = (int)(m * 16.f + 0.5f);     // m*16 in [8,16]
        if (q == 16) { q = 8; ee += 1; }
        if (ee > 15) { ee = 15; q = 15; }   // clamp toward max finite
        r = (uchar_t)((ee << 3) | (q & 7));
    }
    return r | (uchar_t)(s << 7);
#endif
}

__device__ __forceinline__ f2v_t fp8x2_dec_lo(uint_t w) {
#ifdef HAVE_FP8_HW
    return __builtin_amdgcn_cvt_pk_f32_fp8(w, false);
#else
    f2v_t r;
    for (int k = 0; k < 2; ++k) {
        uchar_t b = (w >> (8 * k)) & 0xff;
        uint_t s = (b >> 7) & 1, e = (b >> 3) & 15, m = b & 7;
        float f;
        if (e) { union { uint_t u; float ff; } c;
                 c.u = (s << 31) | ((e + 120) << 23) | (m << 20); f = c.ff; }
        else   { f = (float)m * 0.001953125f; if (s) f = -f; }
        r[k] = f;
    }
    return r;
#endif
}
__device__ __forceinline__ f2v_t fp8x2_dec_hi(uint_t w) {
#ifdef HAVE_FP8_HW
    return __builtin_amdgcn_cvt_pk_f32_fp8(w, true);
#else
    return fp8x2_dec_lo(w >> 16);
#endif
}

// ---------------------------------------------------------------------------
// Sort pass 1: per-block LDS histogram over 196 coarse buckets (dst >> 9).
// ---------------------------------------------------------------------------
__global__ void block_hist_kernel(const int* __restrict__ ei, int E,
                                  int* __restrict__ blockHist) {
    __shared__ int cnt[NB];
    int t = threadIdx.x, blk = blockIdx.x;
    for (int i = t; i < NB; i += 256) cnt[i] = 0;
    __syncthreads();
    int e0 = blk * EPB;
#pragma unroll
    for (int i = 0; i < EPB / 256; ++i) {
        int e = e0 + i * 256 + t;
        if (e < E) atomicAdd(&cnt[ei[E + e] >> BSHIFT], 1);
    }
    __syncthreads();
    for (int i = t; i < NB; i += 256) blockHist[blk * NB + i] = cnt[i];
}

// ---------------------------------------------------------------------------
// Sort pass 2: per-bin exclusive scan down the blocks.
// ---------------------------------------------------------------------------
__global__ void col_scan_kernel(const int* __restrict__ blockHist, int nblk,
                                int* __restrict__ blockBase,
                                int* __restrict__ btot) {
    __shared__ int ss[256];
    __shared__ int carry;
    int bin = blockIdx.x, t = threadIdx.x;
    if (t == 0) carry = 0;
    __syncthreads();
    for (int c0 = 0; c0 < nblk; c0 += 256) {
        int b = c0 + t;
        int v = (b < nblk) ? blockHist[b * NB + bin] : 0;
        ss[t] = v;
        __syncthreads();
        for (int off = 1; off < 256; off <<= 1) {
            int u = (t >= off) ? ss[t - off] : 0;
            __syncthreads();
            ss[t] += u;
            __syncthreads();
        }
        if (b < nblk) blockBase[b * NB + bin] = carry + ss[t] - v;
        __syncthreads();
        if (t == 255) carry += ss[255];
        __syncthreads();
    }
    if (t == 0) btot[bin] = carry;
}

// ---------------------------------------------------------------------------
// Sort pass 3: scatter packed (src<<9 | dst&511) into coarse-bucket order.
// Bucket base offsets computed locally from btot (196-elem LDS scan).
// ---------------------------------------------------------------------------
__global__ void scatter_pairs_kernel(const int* __restrict__ ei, int E,
                                     const int* __restrict__ blockBase,
                                     const int* __restrict__ btot,
                                     uint_t* __restrict__ pairs) {
    __shared__ int cur[NB];
    __shared__ int base[NB];
    __shared__ int ss[256];
    int t = threadIdx.x, blk = blockIdx.x;
    int v = (t < NB) ? btot[t] : 0;
    ss[t] = v;
    __syncthreads();
    for (int off = 1; off < 256; off <<= 1) {
        int u = (t >= off) ? ss[t - off] : 0;
        __syncthreads();
        ss[t] += u;
        __syncthreads();
    }
    if (t < NB) {
        cur[t] = 0;
        base[t] = (ss[t] - v) + blockBase[blk * NB + t];
    }
    __syncthreads();
    int e0 = blk * EPB;
#pragma unroll
    for (int i = 0; i < EPB / 256; ++i) {
        int e = e0 + i * 256 + t;
        if (e < E) {
            int src = ei[e];
            int dst = ei[E + e];
            int bin = dst >> BSHIFT;
            int r = atomicAdd(&cur[bin], 1);   // LDS atomic
            pairs[base[bin] + r] = ((uint_t)src << BSHIFT) | (uint_t)(dst & (BSZ - 1));
        }
    }
}

// ---------------------------------------------------------------------------
// Sort pass 4: per-bucket fine sort. Bucket base computed locally
// from btot; rowptr + contiguous csr region; rowptr[N] written by last bin.
// ---------------------------------------------------------------------------
__global__ void bucket_sort_kernel(const uint_t* __restrict__ pairs,
                                   const int* __restrict__ btot,
                                   int* __restrict__ rowptr,
                                   int* __restrict__ csr) {
    __shared__ int hist[BSZ];
    __shared__ int lofs[BSZ];
    int bin = blockIdx.x, t = threadIdx.x;
    // local exclusive prefix of btot over 196 bins (inclusive scan, then shift)
    int pv = (t < NB) ? btot[t] : 0;
    lofs[t] = pv;
    __syncthreads();
    for (int off = 1; off < BSZ; off <<= 1) {
        int u = (t >= off) ? lofs[t - off] : 0;
        __syncthreads();
        lofs[t] += u;
        __syncthreads();
    }
    int base = (bin > 0) ? lofs[bin - 1] : 0;   // broadcast LDS read
    int cnt = btot[bin];
    __syncthreads();
    hist[t] = 0;
    __syncthreads();
    for (int i = t; i < cnt; i += BSZ)
        atomicAdd(&hist[pairs[base + i] & (BSZ - 1)], 1);
    __syncthreads();
    int v = hist[t];
    lofs[t] = v;
    __syncthreads();
    for (int off = 1; off < BSZ; off <<= 1) {
        int u = (t >= off) ? lofs[t - off] : 0;
        __syncthreads();
        lofs[t] += u;
        __syncthreads();
    }
    int excl = lofs[t] - v;
    int d_global = (bin << BSHIFT) + t;
    if (d_global < N_NODES) rowptr[d_global] = base + excl;
    if (bin == NB - 1 && t == 0) rowptr[N_NODES] = base + cnt;
    __syncthreads();
    lofs[t] = excl;
    hist[t] = 0;
    __syncthreads();
    for (int i = t; i < cnt; i += BSZ) {
        uint_t p = pairs[base + i];
        int lb = p & (BSZ - 1);
        int r = atomicAdd(&hist[lb], 1);
        csr[base + lofs[lb] + r] = (int)(p >> BSHIFT);
    }
}

// ---------------------------------------------------------------------------
// cvt_w: bf16 [n][k]-major weight tensors.
// ---------------------------------------------------------------------------
__global__ void cvt_w_kernel(const float* __restrict__ W1l,
                             const float* __restrict__ W1r,
                             const float* __restrict__ W2l,
                             const float* __restrict__ W2r,
                             ushort_t* __restrict__ W1t,
                             ushort_t* __restrict__ W2t) {
    int t = blockIdx.x * blockDim.x + threadIdx.x;
    if (t < 128 * F_IN) {
        int n = t / F_IN, k = t - n * F_IN;
        float v = (n < HID) ? W1l[k * HID + n] : W1r[k * HID + (n - HID)];
        W1t[t] = f2b(v);
    } else if (t < 128 * F_IN + 80 * HID) {
        int u = t - 128 * F_IN;
        int n = u / HID, k = u - n * HID;
        float v = (n < N_CLS) ? W2l[k * N_CLS + n] : W2r[k * N_CLS + (n - N_CLS)];
        W2t[u] = f2b(v);
    }
}

// ---------------------------------------------------------------------------
// gemm1_mfma: y1(fp8, 64 B rows) | z1(bf16) = x @ [W1_l|W1_r].
// 2 tiles (32 rows) per wave; LDS-staged outputs, contiguous wide stores.
// ---------------------------------------------------------------------------
__global__ void gemm1_mfma_kernel(const float* __restrict__ x,
                                  const ushort_t* __restrict__ W1t,
                                  uchar_t* __restrict__ y1f8,
                                  ushort_t* __restrict__ z1b) {
    __shared__ uchar_t sy[128][80];    // 10240 B, rows padded 64->80
    __shared__ ushort_t sz[128][72];   // 18432 B, rows padded 64->72
    int tid = threadIdx.x;
    int wave = tid >> 6, lane = tid & 63;
    int tile0 = blockIdx.x * 8 + wave * 2;     // 2 consecutive tiles per wave
    int m0b = blockIdx.x * 128;
    int r = lane & 15, q = lane >> 4;
    bool v0 = (tile0 < MT), v1 = (tile0 + 1 < MT);

    bf8_t a0[4], a1[4];
#pragma unroll
    for (int kt = 0; kt < 4; ++kt) { a0[kt] = (bf8_t)(short)0; a1[kt] = (bf8_t)(short)0; }
    if (v0) {
        const float* xr = x + (size_t)(tile0 * 16 + r) * F_IN + q * 8;
#pragma unroll
        for (int kt = 0; kt < 4; ++kt) {
            float4 u = *(const float4*)(xr + kt * 32);
            float4 v = *(const float4*)(xr + kt * 32 + 4);
            bf8_t tt;
            tt[0] = (short)f2b(u.x); tt[1] = (short)f2b(u.y);
            tt[2] = (short)f2b(u.z); tt[3] = (short)f2b(u.w);
            tt[4] = (short)f2b(v.x); tt[5] = (short)f2b(v.y);
            tt[6] = (short)f2b(v.z); tt[7] = (short)f2b(v.w);
            a0[kt] = tt;
        }
    }
    if (v1) {
        const float* xr = x + (size_t)((tile0 + 1) * 16 + r) * F_IN + q * 8;
#pragma unroll
        for (int kt = 0; kt < 4; ++kt) {
            float4 u = *(const float4*)(xr + kt * 32);
            float4 v = *(const float4*)(xr + kt * 32 + 4);
            bf8_t tt;
            tt[0] = (short)f2b(u.x); tt[1] = (short)f2b(u.y);
            tt[2] = (short)f2b(u.z); tt[3] = (short)f2b(u.w);
            tt[4] = (short)f2b(v.x); tt[5] = (short)f2b(v.y);
            tt[6] = (short)f2b(v.z); tt[7] = (short)f2b(v.w);
            a1[kt] = tt;
        }
    }
    int lr0 = wave * 32 + q * 4;       // row base within block for tile 0
#pragma unroll
    for (int tn = 0; tn < 8; ++tn) {
        const ushort_t* wr = W1t + (size_t)(tn * 16 + r) * F_IN + q * 8;
        bf8_t b[4];
#pragma unroll
        for (int kt = 0; kt < 4; ++kt)
            b[kt] = *(const bf8_t*)(wr + kt * 32);
        f4_t acc0 = {0.f, 0.f, 0.f, 0.f};
        f4_t acc1 = {0.f, 0.f, 0.f, 0.f};
#pragma unroll
        for (int kt = 0; kt < 4; ++kt) {
            acc0 = __builtin_amdgcn_mfma_f32_16x16x32_bf16(a0[kt], b[kt], acc0, 0, 0, 0);
            acc1 = __builtin_amdgcn_mfma_f32_16x16x32_bf16(a1[kt], b[kt], acc1, 0, 0, 0);
        }
        int col = tn * 16 + r;
        if (col < 64) {
            if (v0) {
#pragma unroll
                for (int rr = 0; rr < 4; ++rr) sy[lr0 + rr][col] = fp8_enc(acc0[rr]);
            }
            if (v1) {
#pragma unroll
                for (int rr = 0; rr < 4; ++rr) sy[lr0 + 16 + rr][col] = fp8_enc(acc1[rr]);
            }
        } else {
            if (v0) {
#pragma unroll
                for (int rr = 0; rr < 4; ++rr) sz[lr0 + rr][col - 64] = f2b(acc0[rr]);
            }
            if (v1) {
#pragma unroll
                for (int rr = 0; rr < 4; ++rr) sz[lr0 + 16 + rr][col - 64] = f2b(acc1[rr]);
            }
        }
    }
    __syncthreads();
    int vrows = N_NODES - m0b; if (vrows > 128) vrows = 128;
    for (int idx = tid; idx < vrows * 4; idx += 256) {
        int row = idx >> 2, c = (idx & 3) << 4;
        *(uint4*)(y1f8 + (size_t)(m0b + row) * 64 + c) = *(const uint4*)&sy[row][c];
    }
    for (int idx = tid; idx < vrows * 8; idx += 256) {
        int row = idx >> 3, c = (idx & 7) << 3;      // ushort offset, 8 = 16 B
        *(uint4*)(z1b + (size_t)(m0b + row) * HID + c) = *(const uint4*)&sz[row][c];
    }
}

// ---------------------------------------------------------------------------
// agg1: h = relu(mean y1[src] + b1 + z1). Writes h as bf16 (hb, gemm2 A-op)
// AND as fp8 64-B rows (hf8, layer-2 aggregation gather table).
// 4-lane group = one node (16 nodes/wave); lane l owns cols l*16..l*16+15.
// ---------------------------------------------------------------------------
__device__ __forceinline__ void acc16(float* acc, uint4 v) {
    f2v_t p;
    p = fp8x2_dec_lo(v.x); acc[0]  += p[0]; acc[1]  += p[1];
    p = fp8x2_dec_hi(v.x); acc[2]  += p[0]; acc[3]  += p[1];
    p = fp8x2_dec_lo(v.y); acc[4]  += p[0]; acc[5]  += p[1];
    p = fp8x2_dec_hi(v.y); acc[6]  += p[0]; acc[7]  += p[1];
    p = fp8x2_dec_lo(v.z); acc[8]  += p[0]; acc[9]  += p[1];
    p = fp8x2_dec_hi(v.z); acc[10] += p[0]; acc[11] += p[1];
    p = fp8x2_dec_lo(v.w); acc[12] += p[0]; acc[13] += p[1];
    p = fp8x2_dec_hi(v.w); acc[14] += p[0]; acc[15] += p[1];
}

__global__ void agg1_kernel(const int* __restrict__ rowptr,
                            const int* __restrict__ csr,
                            const uchar_t* __restrict__ y1f8,
                            const ushort_t* __restrict__ z1b,
                            const float* __restrict__ b1,
                            ushort_t* __restrict__ hb,
                            uchar_t* __restrict__ hf8) {
    int gid = blockIdx.x * blockDim.x + threadIdx.x;
    int wave = gid >> 6, lane = gid & 63;
    int g = lane >> 2, l = lane & 3;
    int n = wave * 16 + g;                // N_NODES % 16 == 0
    if (n >= N_NODES) return;
    int beg = rowptr[n], end = rowptr[n + 1];
    float acc[16];
#pragma unroll
    for (int j = 0; j < 16; ++j) acc[j] = 0.f;
    const uchar_t* yb = y1f8 + l * 16;
    int i = beg;
    for (; i + 3 < end; i += 4) {
        int s0 = csr[i], s1 = csr[i + 1], s2 = csr[i + 2], s3 = csr[i + 3];
        uint4 w0 = *(const uint4*)(yb + (size_t)s0 * 64);
        uint4 w1 = *(const uint4*)(yb + (size_t)s1 * 64);
        uint4 w2 = *(const uint4*)(yb + (size_t)s2 * 64);
        uint4 w3 = *(const uint4*)(yb + (size_t)s3 * 64);
        acc16(acc, w0); acc16(acc, w1); acc16(acc, w2); acc16(acc, w3);
    }
    for (; i < end; ++i) {
        uint4 w = *(const uint4*)(yb + (size_t)csr[i] * 64);
        acc16(acc, w);
    }
    float inv = 1.0f / fmaxf((float)(end - beg), 1.0f);
    int c = l * 16;
    ushort_t zz[16];
    *(uint4*)&zz[0] = *(const uint4*)(z1b + (size_t)n * HID + c);
    *(uint4*)&zz[8] = *(const uint4*)(z1b + (size_t)n * HID + c + 8);
    float bv[16];
    *(float4*)&bv[0]  = *(const float4*)(b1 + c);
    *(float4*)&bv[4]  = *(const float4*)(b1 + c + 4);
    *(float4*)&bv[8]  = *(const float4*)(b1 + c + 8);
    *(float4*)&bv[12] = *(const float4*)(b1 + c + 12);
    ushort_t o[16];
    uchar_t of[16];
#pragma unroll
    for (int j = 0; j < 16; ++j) {
        float r = fmaxf(fmaf(acc[j], inv, bv[j] + b2f(zz[j])), 0.f);
        o[j] = f2b(r);
        of[j] = fp8_enc(r);
    }
    *(uint4*)(hb + (size_t)n * HID + c)     = *(const uint4*)&o[0];
    *(uint4*)(hb + (size_t)n * HID + c + 8) = *(const uint4*)&o[8];
    *(uint4*)(hf8 + (size_t)n * 64 + c)     = *(const uint4*)&of[0];
}

// ---------------------------------------------------------------------------
// agg2m: mean_h[n] = mean over neighbors of hf8[src] (linearity: aggregation
// commutes with the linear layer, so aggregate h instead of h@W2l).
// Identical structure to agg1 (the proven fast gather shape).
// ---------------------------------------------------------------------------
__global__ void agg2m_kernel(const int* __restrict__ rowptr,
                             const int* __restrict__ csr,
                             const uchar_t* __restrict__ hf8,
                             ushort_t* __restrict__ mb) {
    int gid = blockIdx.x * blockDim.x + threadIdx.x;
    int wave = gid >> 6, lane = gid & 63;
    int g = lane >> 2, l = lane & 3;
    int n = wave * 16 + g;
    if (n >= N_NODES) return;
    int beg = rowptr[n], end = rowptr[n + 1];
    float acc[16];
#pragma unroll
    for (int j = 0; j < 16; ++j) acc[j] = 0.f;
    const uchar_t* yb = hf8 + l * 16;
    int i = beg;
    for (; i + 3 < end; i += 4) {
        int s0 = csr[i], s1 = csr[i + 1], s2 = csr[i + 2], s3 = csr[i + 3];
        uint4 w0 = *(const uint4*)(yb + (size_t)s0 * 64);
        uint4 w1 = *(const uint4*)(yb + (size_t)s1 * 64);
        uint4 w2 = *(const uint4*)(yb + (size_t)s2 * 64);
        uint4 w3 = *(const uint4*)(yb + (size_t)s3 * 64);
        acc16(acc, w0); acc16(acc, w1); acc16(acc, w2); acc16(acc, w3);
    }
    for (; i < end; ++i) {
        uint4 w = *(const uint4*)(yb + (size_t)csr[i] * 64);
        acc16(acc, w);
    }
    float inv = 1.0f / fmaxf((float)(end - beg), 1.0f);
    int c = l * 16;
    ushort_t o[16];
#pragma unroll
    for (int j = 0; j < 16; ++j)
        o[j] = f2b(acc[j] * inv);
    *(uint4*)(mb + (size_t)n * HID + c)     = *(const uint4*)&o[0];
    *(uint4*)(mb + (size_t)n * HID + c + 8) = *(const uint4*)&o[8];
}

// ---------------------------------------------------------------------------
// gemm2_fused: out = log_softmax(mean_h @ W2l + h @ W2r + b2).
// Both products accumulate into the same MFMA C-fragment. Softmax reduces
// across the 16 r-lanes (rows live in acc[rr], cols in lane r + tn).
// LDS-staged f32 output block for contiguous stores.
// ---------------------------------------------------------------------------
__global__ void gemm2_fused_kernel(const ushort_t* __restrict__ mb,
                                   const ushort_t* __restrict__ hb,
                                   const ushort_t* __restrict__ W2t,
                                   const float* __restrict__ b2,
                                   float* __restrict__ out) {
    __shared__ float sOut[64][44];     // 11264 B, rows padded 40->44
    int tid = threadIdx.x;
    int wave = tid >> 6, lane = tid & 63;
    int tile = blockIdx.x * 4 + wave;
    int m0b = blockIdx.x * 64;
    if (tile < MT) {
        int m0 = tile * 16;
        int r = lane & 15, q = lane >> 4;
        const ushort_t* mr = mb + (size_t)(m0 + r) * HID + q * 8;
        const ushort_t* hr = hb + (size_t)(m0 + r) * HID + q * 8;
        bf8_t a0[2], a1[2];
#pragma unroll
        for (int kt = 0; kt < 2; ++kt) {
            a0[kt] = *(const bf8_t*)(mr + kt * 32);
            a1[kt] = *(const bf8_t*)(hr + kt * 32);
        }
        float v[3][4];
#pragma unroll
        for (int tn = 0; tn < 3; ++tn) {
            int col = tn * 16 + r;
            int cl = (col < N_CLS) ? col : 0;      // clamp; masked below
            const ushort_t* wl = W2t + (size_t)cl * HID + q * 8;
            const ushort_t* wrp = W2t + (size_t)(N_CLS + cl) * HID + q * 8;
            f4_t acc = {0.f, 0.f, 0.f, 0.f};
#pragma unroll
            for (int kt = 0; kt < 2; ++kt) {
                bf8_t bl = *(const bf8_t*)(wl + kt * 32);
                acc = __builtin_amdgcn_mfma_f32_16x16x32_bf16(a0[kt], bl, acc, 0, 0, 0);
            }
#pragma unroll
            for (int kt = 0; kt < 2; ++kt) {
                bf8_t br = *(const bf8_t*)(wrp + kt * 32);
                acc = __builtin_amdgcn_mfma_f32_16x16x32_bf16(a1[kt], br, acc, 0, 0, 0);
            }
            float bias = (col < N_CLS) ? b2[cl] : 0.f;
#pragma unroll
            for (int rr = 0; rr < 4; ++rr)
                v[tn][rr] = (col < N_CLS) ? (acc[rr] + bias) : -INFINITY;
        }
        // log_softmax per row (row = q*4+rr): reduce over tn (local) and the
        // 16 r-lanes (xor offsets 1,2,4,8 stay within the same q group).
        int lrow = wave * 16 + q * 4;
#pragma unroll
        for (int rr = 0; rr < 4; ++rr) {
            float m = fmaxf(fmaxf(v[0][rr], v[1][rr]), v[2][rr]);
#pragma unroll
            for (int off = 1; off < 16; off <<= 1)
                m = fmaxf(m, __shfl_xor(m, off, 64));
            float s = 0.f;
#pragma unroll
            for (int tn = 0; tn < 3; ++tn)
                if (v[tn][rr] > -INFINITY) s += expf(v[tn][rr] - m);
#pragma unroll
            for (int off = 1; off < 16; off <<= 1)
                s += __shfl_xor(s, off, 64);
            float ls = m + logf(s);
#pragma unroll
            for (int tn = 0; tn < 3; ++tn) {
                int col = tn * 16 + r;
                if (col < N_CLS)
                    sOut[lrow + rr][col] = v[tn][rr] - ls;
            }
        }
    }
    __syncthreads();
    int vrows = N_NODES - m0b; if (vrows > 64) vrows = 64;
    for (int idx = tid; idx < vrows * 10; idx += 256) {
        int row = idx / 10, c = (idx - row * 10) * 4;   // floats; 4 = 16 B
        *(float4*)(out + (size_t)(m0b + row) * N_CLS + c) = *(const float4*)&sOut[row][c];
    }
}

extern "C" void kernel_launch(void* const* d_in, const int* in_sizes, int n_in,
                              void* d_out, int out_size, void* d_ws, size_t ws_size,
                              hipStream_t stream) {
    const float* x   = (const float*)d_in[0];
    const int*   ei  = (const int*)d_in[1];
    const float* W1l = (const float*)d_in[2];
    const float* b1  = (const float*)d_in[3];
    const float* W1r = (const float*)d_in[4];
    const float* W2l = (const float*)d_in[5];
    const float* b2  = (const float*)d_in[6];
    const float* W2r = (const float*)d_in[7];
    float* out = (float*)d_out;
    const int E = in_sizes[1] / 2;
    const int nblk = (E + EPB - 1) / EPB;

    char* p = (char*)d_ws;
    auto take = [&](size_t bytes) {
        char* q = p;
        p += (bytes + 15) & ~(size_t)15;
        return (void*)q;
    };
    int* rowptr     = (int*)take(sizeof(int) * (N_NODES + 4));
    int* blockHist  = (int*)take(sizeof(int) * (size_t)nblk * NB);
    int* blockBase  = (int*)take(sizeof(int) * (size_t)nblk * NB);
    int* btot       = (int*)take(sizeof(int) * NB);
    uint_t* pairs   = (uint_t*)take(sizeof(uint_t) * (size_t)E);
    int* csr        = (int*)take(sizeof(int) * (size_t)E);
    ushort_t* W1t   = (ushort_t*)take(sizeof(ushort_t) * 128 * F_IN);
    ushort_t* W2t   = (ushort_t*)take(sizeof(ushort_t) * 80 * HID);
    uchar_t* y1f8   = (uchar_t*)take(sizeof(uchar_t) * (size_t)N_NODES * 64);
    ushort_t* z1b   = (ushort_t*)take(sizeof(ushort_t) * (size_t)N_NODES * HID);
    ushort_t* hb    = (ushort_t*)take(sizeof(ushort_t) * (size_t)N_NODES * HID);
    uchar_t* hf8    = (uchar_t*)take(sizeof(uchar_t) * (size_t)N_NODES * 64);
    ushort_t* mb    = (ushort_t*)take(sizeof(ushort_t) * (size_t)N_NODES * HID);

    const int B = 256;

    block_hist_kernel<<<nblk, 256, 0, stream>>>(ei, E, blockHist);
    col_scan_kernel<<<NB, 256, 0, stream>>>(blockHist, nblk, blockBase, btot);
    scatter_pairs_kernel<<<nblk, 256, 0, stream>>>(ei, E, blockBase, btot, pairs);
    bucket_sort_kernel<<<NB, BSZ, 0, stream>>>(pairs, btot, rowptr, csr);

    cvt_w_kernel<<<(128 * F_IN + 80 * HID + B - 1) / B, B, 0, stream>>>(
        W1l, W1r, W2l, W2r, W1t, W2t);

    int gemm1_blocks = (MT + 7) / 8;    // 8 tiles (128 rows) per block
    int gemm2_blocks = (MT + 3) / 4;    // 4 tiles (64 rows) per block
    int t_agg = (N_NODES / 16) * 64;    // 16 nodes per wave (4-lane groups)

    gemm1_mfma_kernel<<<gemm1_blocks, B, 0, stream>>>(x, W1t, y1f8, z1b);
    agg1_kernel<<<(t_agg + B - 1) / B, B, 0, stream>>>(rowptr, csr, y1f8, z1b, b1, hb, hf8);
    agg2m_kernel<<<(t_agg + B - 1) / B, B, 0, stream>>>(rowptr, csr, hf8, mb);
    gemm2_fused_kernel<<<gemm2_blocks, B, 0, stream>>>(mb, hb, W2t, b2, out);
}